// Round 8
// baseline (898.372 us; speedup 1.0000x reference)
//
#include <hip/hip_runtime.h>
#include <stdint.h>

#define NN   16384
#define HID  256
#define LDSK 264            // padded LDS row stride in f16 elems (gemm body)
#define NSLICE 16           // j sliced 16-way
#define JSL  (NN/NSLICE)    // 1024 j's per slice
#define JT   32             // j-tile rows, 16KB tiles, double-buffered (R5-proven)
#define NIT  (JSL/JT)       // 32 iterations per block
#define NSETS 4             // R6-proven: LDS bytes/eval halved, no spill at (256,2)
#define ITILE (NSETS*64)    // 256 i's per block
#define NRS  8              // exact-rescore chains (top-8 of 64 by scan key)
#define GSB  2048           // grid-stride block count for efeat/fin (R8: was 16384 blocks)
#define FLTMAX 3.402823466e38f
#define KEYMAX 0xFFFFFFFFu
#define VBIAS 131072.0f     // folded into sqj64; keeps v64+B > 0 for ALL pairs incl. self
#define MSTRIDE 17          // padded merge stride (u32): tid*17 reads are conflict-free

typedef __attribute__((ext_vector_type(8))) _Float16 f16x8;
typedef __attribute__((ext_vector_type(4))) _Float16 f16x4;
typedef __attribute__((ext_vector_type(4))) float f32x4;

typedef const __attribute__((address_space(1))) unsigned int* gAS1;
typedef __attribute__((address_space(3))) unsigned int* lAS3;

// ---- fused fp32->fp16 convert (x, W1, W2) + np-replicating row sum-of-squares
// ---- + Bdeg/done zeroing (R8: replaces hipMemsetAsync) ----
#define NXG (NN*HID/4)
#define NWG (HID*HID/4)
#define CVTB ((NXG + 2*NWG)/256)     // 4224 cvt blocks
__global__ __launch_bounds__(256) void prep_kernel(const float* __restrict__ x,
                                                   const float* __restrict__ W1,
                                                   const float* __restrict__ W2,
                                                   _Float16* __restrict__ xh,
                                                   _Float16* __restrict__ W1h,
                                                   _Float16* __restrict__ W2h,
                                                   float* __restrict__ sqf,
                                                   int* __restrict__ Bdeg,
                                                   int* __restrict__ done){
  #pragma clang fp contract(off)
  int b = blockIdx.x;
  int g0 = b * 256 + threadIdx.x;
  if (g0 < NN) Bdeg[g0] = 0;
  if (g0 == 0) *done = 0;
  if (b < CVTB){
    int g = g0;
    const float* src; _Float16* dst; int o;
    if (g < NXG)            { src = x;  dst = xh;  o = g; }
    else if (g < NXG + NWG) { src = W1; dst = W1h; o = g - NXG; }
    else                    { src = W2; dst = W2h; o = g - NXG - NWG; }
    float4 v = ((const float4*)src)[o];
    f16x4 h; h.x = (_Float16)v.x; h.y = (_Float16)v.y; h.z = (_Float16)v.z; h.w = (_Float16)v.w;
    ((f16x4*)dst)[o] = h;
  } else {
    int bb = b - CVTB;
    int lane = threadIdx.x & 63;
    int rw   = lane >> 4;
    int h    = (lane >> 3) & 1;
    int j    = lane & 7;
    int row  = (bb * 4 + (threadIdx.x >> 6)) * 4 + rw;
    const float* p = x + (size_t)row * HID + h*128 + j;
    float v0 = p[0];
    float r  = v0 * v0;
    #pragma unroll
    for (int i = 1; i < 16; ++i){ float v = p[i*8]; float m = v * v; r = r + m; }
    float t1 = r  + __shfl_xor(r,  1);
    float t2 = t1 + __shfl_xor(t1, 2);
    float t3 = t2 + __shfl_xor(t2, 4);
    float tot = t3 + __shfl_xor(t3, 8);
    if (h == 0 && j == 0) sqf[row] = tot;
  }
}

// stage 64x256 f16 tile into LDS with padded stride (256 threads) — gemm body
__device__ __forceinline__ void load_tile64(unsigned short* dst, const unsigned short* src, int tid){
  const uint4* s = (const uint4*)src;
  #pragma unroll
  for (int r = 0; r < 8; ++r){
    int fl  = tid + (r << 8);
    int row = fl >> 5;
    int c   = fl & 31;
    *(uint4*)&dst[row*LDSK + (c << 3)] = s[fl];
  }
}

// 4-op sorted-ascending top-4 insert (R6-proven):
// b0'=min(k,b0); bN'=med3(k,b(N-1),bN)
__device__ __forceinline__ unsigned umed3(unsigned a, unsigned b, unsigned c){
  unsigned d;
  asm("v_med3_u32 %0, %1, %2, %3" : "=v"(d) : "v"(a), "v"(b), "v"(c));
  return d;
}
__device__ __forceinline__ void ins4(unsigned (&b)[4], unsigned k){
  unsigned b0 = b[0], b1 = b[1], b2 = b[2];
  b[0] = k < b0 ? k : b0;          // v_min_u32
  b[1] = umed3(k, b0, b1);
  b[2] = umed3(k, b1, b2);
  b[3] = umed3(k, b2, b[3]);
}

// fp16 MFMA Gram, swapped operands, FOUR stationary i-sets/wave (R6-proven).
// XOR-swizzled row-major LDS + double-buffered 32-row tiles (R5-proven).
// Packed u32 scan key + VBIAS fold, self dropped in rescore (R3/R4-proven).
// BYTE-IDENTICAL to the R6-verified kernel.
__global__ __launch_bounds__(256, 2) void knn_kernel(const _Float16* __restrict__ xh,
                                                     const float* __restrict__ sqf,
                                                     unsigned* __restrict__ candk){
  __shared__ __align__(16) unsigned short Xj[2][JT*256];  // 2 x 16KB swizzled tiles; aliased as merge buf
  __shared__ __align__(16) float sqj64[2][JT];            // sq_j*64 + VBIAS, double-buffered

  int tid  = threadIdx.x;
  int sl   = blockIdx.x & (NSLICE-1);
  int i0   = (blockIdx.x / NSLICE) * ITILE;
  int jb0  = sl * JSL;
  int wave = tid >> 6, lane = tid & 63, quad = lane >> 4, lcol = lane & 15;

  f16x8 bfr[NSETS][8];
  #pragma unroll
  for (int s = 0; s < NSETS; ++s){
    const _Float16* br = xh + (size_t)(i0 + s*64 + wave*16 + lcol) * HID + quad*8;
    #pragma unroll
    for (int ks = 0; ks < 8; ++ks) bfr[s][ks] = *(const f16x8*)(br + ks*32);
  }

  const _Float16* gsrc[4];
  #pragma unroll
  for (int r = 0; r < 4; ++r){
    int m   = r*256 + tid;
    int row = m >> 5;
    int ch  = m & 31;
    gsrc[r] = xh + (size_t)row * HID + ((ch ^ (row & 7)) << 3);
  }

  int b0 = lcol*512 + ((quad ^ (lcol & 3)) << 4) + (((lcol >> 2) & 1) << 6);
  int b1 = b0 ^ 64;

  unsigned bk[NSETS][4];
  #pragma unroll
  for (int s = 0; s < NSETS; ++s)
    #pragma unroll
    for (int e = 0; e < 4; ++e) bk[s][e] = KEYMAX;

  {
    size_t joff = (size_t)jb0 * HID;
    #pragma unroll
    for (int r = 0; r < 4; ++r)
      __builtin_amdgcn_global_load_lds((gAS1)(const void*)(gsrc[r] + joff),
                                       (lAS3)(void*)&Xj[0][(r*256 + tid) * 8],
                                       16, 0, 0);
    if (tid < JT) sqj64[0][tid] = fmaf(sqf[jb0 + tid], 64.f, VBIAS);
  }
  __syncthreads();

  for (int it = 0; it < NIT; ++it){
    if (it + 1 < NIT){
      int nb = (it + 1) & 1;
      int jn = jb0 + (it + 1) * JT;
      size_t joff = (size_t)jn * HID;
      #pragma unroll
      for (int r = 0; r < 4; ++r)
        __builtin_amdgcn_global_load_lds((gAS1)(const void*)(gsrc[r] + joff),
                                         (lAS3)(void*)&Xj[nb][(r*256 + tid) * 8],
                                         16, 0, 0);
      if (tid < JT) sqj64[nb][tid] = fmaf(sqf[jn + tid], 64.f, VBIAS);
    }

    const char*  tb  = (const char*)&Xj[it & 1][0];
    const float* sjb = sqj64[it & 1];
    int jb = jb0 + it * JT;

    #pragma unroll
    for (int sub = 0; sub < 2; ++sub){
      f32x4 acc[NSETS];
      #pragma unroll
      for (int s = 0; s < NSETS; ++s) acc[s] = (f32x4){0.f,0.f,0.f,0.f};
      #pragma unroll
      for (int ks = 0; ks < 8; ++ks){
        f16x8 a = *(const f16x8*)(tb + sub*8192 + ((ks >> 1) << 7) + ((ks & 1) ? b1 : b0));
        #pragma unroll
        for (int s = 0; s < NSETS; ++s)
          acc[s] = __builtin_amdgcn_mfma_f32_16x16x32_f16(a, bfr[s][ks], acc[s], 0, 0, 0);
      }
      float4 sj4 = *(const float4*)&sjb[sub*16 + quad*4];
      int jbase = jb + sub*16 + quad*4;
      #pragma unroll
      for (int reg = 0; reg < 4; ++reg){
        int gj = jbase + reg;
        float sj = (&sj4.x)[reg];
        #pragma unroll
        for (int s = 0; s < NSETS; ++s){
          float v64 = fmaf(-128.f, acc[s][reg], sj);   // (sj - 2*dot)*64 + VBIAS > 0 always
          unsigned kv = (unsigned)v64;                 // v_cvt_u32_f32
          unsigned key = (kv << 14) + (unsigned)gj;    // v_lshl_add_u32
          ins4(bk[s], key);
        }
      }
    }
    __syncthreads();   // implicit vmcnt(0): drains the prefetch issued ABOVE (old)
  }

  unsigned* Mk = (unsigned*)Xj;            // ITILE x 17 u32 = 17408 B (<= 32768)
  #pragma unroll
  for (int s = 0; s < NSETS; ++s){
    int base = (s*64 + wave*16 + lcol)*MSTRIDE + quad*4;
    #pragma unroll
    for (int e = 0; e < 4; ++e) Mk[base+e] = bk[s][e];
  }
  __syncthreads();
  if (tid < ITILE){
    unsigned fk[4];
    #pragma unroll
    for (int e = 0; e < 4; ++e) fk[e] = KEYMAX;
    #pragma unroll
    for (int s = 0; s < 16; ++s) ins4(fk, Mk[tid*MSTRIDE + s]);
    int g = i0 + tid;
    #pragma unroll
    for (int e = 0; e < 4; ++e)
      candk[(size_t)g*(NSLICE*4) + sl*4 + e] = fk[e];
  }
}

// Rescore (R6-verified math) + R8: the last-finishing block performs the
// prefix scan (offE/cursor from Bdeg) — standard last-block pattern:
// release threadfence -> atomicAdd(done) -> last block acquire threadfence ->
// 64-thread scan. No dispatch-order or co-residency assumption (some block is
// always last); counter is a device-scope atomic. Removes one kernel boundary.
__global__ __launch_bounds__(64) void rescore_kernel(const float* __restrict__ x,
                                                     const float* __restrict__ sqf,
                                                     const unsigned* __restrict__ candk,
                                                     int* __restrict__ idx_out,
                                                     int* __restrict__ Bdeg,
                                                     int* __restrict__ offE,
                                                     int* __restrict__ cursor,
                                                     int* __restrict__ done){
  #pragma clang fp contract(off)
  __shared__ float Xi[256];
  __shared__ float Xct[256][NRS+1];   // transposed candidate rows, 9.2 KB
  __shared__ float dex[NRS];
  __shared__ int   sel[NRS];
  __shared__ int   lastFlag;
  int i = blockIdx.x;
  int t = threadIdx.x;            // 0..63
  ((float4*)Xi)[t] = ((const float4*)(x + (size_t)i * HID))[t];
  unsigned kv = candk[(size_t)i*(NSLICE*4) + t];
  if ((kv & 16383u) == (unsigned)i) kv = KEYMAX;   // drop self
  int rank = 0;
  for (int s = 0; s < 64; ++s){
    unsigned ks = __shfl(kv, s);
    rank += (ks < kv) ? 1 : 0;
  }
  if (rank < NRS) sel[rank] = (int)(kv & 16383u);
  __syncthreads();
  {
    int r = t >> 3, seg = t & 7;     // 8 rows x 8 segments
    const float4* src = (const float4*)(x + (size_t)sel[r] * HID);
    #pragma unroll
    for (int m = 0; m < 8; ++m){
      float4 v = src[seg + 8*m];
      int k = 4*(seg + 8*m);
      Xct[k+0][r] = v.x; Xct[k+1][r] = v.y; Xct[k+2][r] = v.z; Xct[k+3][r] = v.w;
    }
  }
  __syncthreads();
  if (t < NRS){
    int j = sel[t];
    float acc = 0.f;
    for (int k = 0; k < 256; ++k) acc = fmaf(Xi[k], Xct[k][t], acc);
    float t1   = sqf[i] + sqf[j];
    float twod = 2.0f * acc;
    dex[t] = t1 - twod;
  }
  __syncthreads();
  if (t == 0){
    unsigned taken = 0;
    #pragma unroll
    for (int k = 0; k < 4; ++k){
      float bdv = FLTMAX; int bj = 0x7fffffff, bs = -1;
      for (int s = 0; s < NRS; ++s){
        if (taken & (1u << s)) continue;
        float d = dex[s]; int j = sel[s];
        if (d < bdv || (d == bdv && j < bj)){ bdv = d; bj = j; bs = s; }
      }
      taken |= 1u << bs;
      idx_out[i*4 + k] = bj;
      atomicAdd(&Bdeg[bj], 1);
    }
    __threadfence();                          // release idx/Bdeg
    int old = atomicAdd(done, 1);
    lastFlag = (old == NN - 1) ? 1 : 0;
  }
  __syncthreads();
  if (lastFlag){
    __threadfence();                          // acquire all blocks' Bdeg
    int base = t * 256;
    int s = 0;
    #pragma unroll 8
    for (int k = 0; k < 256; ++k) s += Bdeg[base + k];
    // 64-lane exclusive scan of per-thread sums
    int inc = s;
    #pragma unroll
    for (int d = 1; d < 64; d <<= 1){
      int v = __shfl_up(inc, d);
      if (t >= d) inc += v;
    }
    int a = inc - s;
    for (int k = 0; k < 256; ++k){
      int dv = Bdeg[base + k];
      offE[base + k] = a; cursor[base + k] = a; a += dv;
    }
  }
}

// out[i][o] = sum_k A[i][k] * W[o][k]   (A: Mx256 f16, W staged f16, out f16)
__global__ __launch_bounds__(256) void gemm_xw(const _Float16* __restrict__ A,
                                               const _Float16* __restrict__ W,
                                               _Float16* __restrict__ out){
  __shared__ unsigned short Ws[64 * LDSK];
  int tid = threadIdx.x;
  int i0 = (blockIdx.x >> 2) * 64;
  int o0 = (blockIdx.x & 3)  * 64;
  int wave = tid >> 6, lane = tid & 63, quad = lane >> 4, lcol = lane & 15;
  load_tile64(Ws, (const unsigned short*)(W + (size_t)o0 * HID), tid);
  f16x8 a[8];
  const _Float16* arow = A + (size_t)(i0 + wave*16 + lcol) * HID + quad*8;
  #pragma unroll
  for (int ks = 0; ks < 8; ++ks) a[ks] = *(const f16x8*)(arow + ks*32);
  __syncthreads();
  #pragma unroll
  for (int sub = 0; sub < 4; ++sub){
    f32x4 acc = {0.f, 0.f, 0.f, 0.f};
    #pragma unroll
    for (int ks = 0; ks < 8; ++ks){
      f16x8 b = *(const f16x8*)&Ws[(sub*16 + lcol)*LDSK + quad*8 + ks*32];
      acc = __builtin_amdgcn_mfma_f32_16x16x32_f16(a[ks], b, acc, 0, 0, 0);
    }
    #pragma unroll
    for (int reg = 0; reg < 4; ++reg)
      out[(size_t)(i0 + wave*16 + quad*4 + reg)*HID + o0 + sub*16 + lcol] = (_Float16)acc[reg];
  }
}

__global__ __launch_bounds__(256) void fill_kernel(const int* __restrict__ idx,
                                                   int* __restrict__ cursor,
                                                   int* __restrict__ rev){
  int i = blockIdx.x * 256 + threadIdx.x;
  #pragma unroll
  for (int t = 0; t < 4; ++t){
    int e = idx[i*4 + t];
    int p = atomicAdd(&cursor[e], 1);
    rev[p] = i;
  }
}

// E[e] = mean over contributing nodes of xt[node]  (gather via reverse CSR)
// R8: grid-stride over GSB blocks (was one block per edge = 16384 dispatches)
__global__ __launch_bounds__(256) void efeat_kernel(const _Float16* __restrict__ xt,
                                                    const int* __restrict__ off,
                                                    const int* __restrict__ deg,
                                                    const int* __restrict__ rev,
                                                    _Float16* __restrict__ E){
  int c = threadIdx.x;
  for (int e = blockIdx.x; e < NN; e += GSB){
    int o = off[e], d = deg[e];
    float s = 0.f;
    for (int k = 0; k < d; ++k) s += (float)xt[(size_t)rev[o + k]*HID + c];
    E[(size_t)e*HID + c] = (_Float16)((d > 0) ? s / (float)d : 0.f);
  }
}

__global__ __launch_bounds__(256) void fin1_kernel(const _Float16* __restrict__ E,
                                                   const int* __restrict__ idx,
                                                   const float* __restrict__ b1,
                                                   const float* __restrict__ pa,
                                                   _Float16* __restrict__ h1){
  int c = threadIdx.x;
  float bc = b1[c];
  float a  = pa[0];
  for (int i = blockIdx.x; i < NN; i += GSB){
    const int* ip = idx + i*4;
    float s = (float)E[(size_t)ip[0]*HID + c] + (float)E[(size_t)ip[1]*HID + c]
            + (float)E[(size_t)ip[2]*HID + c] + (float)E[(size_t)ip[3]*HID + c];
    float acc = 0.25f * s + bc;
    acc = (acc >= 0.f) ? acc : a * acc;
    h1[(size_t)i*HID + c] = (_Float16)acc;
  }
}

__global__ __launch_bounds__(256) void fin2_kernel(const _Float16* __restrict__ E,
                                                   const int* __restrict__ idx,
                                                   const float* __restrict__ b2,
                                                   const float* __restrict__ x,
                                                   const float* __restrict__ pa,
                                                   float* __restrict__ out){
  int c = threadIdx.x;
  float bc = b2[c];
  float a  = pa[0];
  for (int i = blockIdx.x; i < NN; i += GSB){
    const int* ip = idx + i*4;
    float s = (float)E[(size_t)ip[0]*HID + c] + (float)E[(size_t)ip[1]*HID + c]
            + (float)E[(size_t)ip[2]*HID + c] + (float)E[(size_t)ip[3]*HID + c];
    float acc = 0.25f * s + bc + x[(size_t)i*HID + c];
    acc = (acc >= 0.f) ? acc : a * acc;
    out[(size_t)i*HID + c] = acc;
  }
}

extern "C" void kernel_launch(void* const* d_in, const int* in_sizes, int n_in,
                              void* d_out, int out_size, void* d_ws, size_t ws_size,
                              hipStream_t stream){
  (void)in_sizes; (void)n_in; (void)out_size; (void)ws_size;
  const float* x  = (const float*)d_in[0];
  // d_in[1] = edge_index (int32), unused by the math
  const float* W1 = (const float*)d_in[2];
  const float* b1 = (const float*)d_in[3];
  const float* W2 = (const float*)d_in[4];
  const float* b2 = (const float*)d_in[5];
  const float* pa = (const float*)d_in[6];
  float* out = (float*)d_out;

  char* ws = (char*)d_ws;
  float*  sqf    = (float*) (ws + 0);                        //  64 KB
  int*    idx    = (int*)   (ws + 65536);                    // 256 KB
  int*    Bdeg   = (int*)   (ws + 327680);                   //  64 KB
  int*    offE   = (int*)   (ws + 393216);                   //  64 KB
  int*    cursor = (int*)   (ws + 458752);                   //  64 KB
  int*    rev    = (int*)   (ws + 524288);                   // 256 KB
  int*    done   = (int*)   (ws + 786432);                   //   4 B
  _Float16* xh   = (_Float16*)(ws + (size_t)(5<<20));        //   8 MB
  _Float16* W1h  = (_Float16*)(ws + (size_t)(13<<20));       // 128 KB
  _Float16* W2h  = (_Float16*)(ws + (size_t)(13<<20) + 131072);
  _Float16* xt   = (_Float16*)(ws + (size_t)(13<<20) + 262144);            // 8 MB
  _Float16* E    = (_Float16*)(ws + (size_t)(21<<20) + 262144);            // 8 MB
  _Float16* h1   = (_Float16*)(ws + (size_t)(29<<20) + 262144);            // 8 MB
  // candk (NN*64*4B = 4 MB) aliases the xt region: dead until the first
  // gemm_xw (which runs after rescore consumed it) -> no ws growth.
  unsigned* candk = (unsigned*)xt;                           // 4 MB

  prep_kernel   <<<CVTB + NN/16, 256, 0, stream>>>(x, W1, W2, xh, W1h, W2h, sqf, Bdeg, done);
  knn_kernel    <<<(NN/ITILE)*NSLICE, 256, 0, stream>>>(xh, sqf, candk);
  rescore_kernel<<<NN, 64, 0, stream>>>(x, sqf, candk, idx, Bdeg, offE, cursor, done);
  fill_kernel   <<<NN/256, 256, 0, stream>>>(idx, cursor, rev);

  gemm_xw       <<<(NN/64)*4, 256, 0, stream>>>(xh, W1h, xt);
  efeat_kernel  <<<GSB, 256, 0, stream>>>(xt, offE, Bdeg, rev, E);
  fin1_kernel   <<<GSB, 256, 0, stream>>>(E, idx, b1, pa, h1);

  gemm_xw       <<<(NN/64)*4, 256, 0, stream>>>(h1, W2h, xt);
  efeat_kernel  <<<GSB, 256, 0, stream>>>(xt, offE, Bdeg, rev, E);
  fin2_kernel   <<<GSB, 256, 0, stream>>>(E, idx, b2, x, pa, out);
}

// Round 9
// 572.779 us; speedup vs baseline: 1.5684x; 1.5684x over previous
//
#include <hip/hip_runtime.h>
#include <stdint.h>

#define NN   16384
#define HID  256
#define LDSK 264            // padded LDS row stride in f16 elems (gemm body)
#define NSLICE 16           // j sliced 16-way
#define JSL  (NN/NSLICE)    // 1024 j's per slice
#define JT   32             // j-tile rows, 16KB tiles, double-buffered (R5-proven)
#define NIT  (JSL/JT)       // 32 iterations per block
#define NSETS 4             // R6-proven: LDS bytes/eval halved, no spill at (256,2)
#define ITILE (NSETS*64)    // 256 i's per block
#define NRS  8              // exact-rescore chains (top-8 of 64 by scan key)
#define GSB  2048           // grid-stride block count for efeat/fin
#define FLTMAX 3.402823466e38f
#define KEYMAX 0xFFFFFFFFu
#define VBIAS 131072.0f     // folded into sqj64; keeps v64+B > 0 for ALL pairs incl. self
#define MSTRIDE 17          // padded merge stride (u32): tid*17 reads are conflict-free

typedef __attribute__((ext_vector_type(8))) _Float16 f16x8;
typedef __attribute__((ext_vector_type(4))) _Float16 f16x4;
typedef __attribute__((ext_vector_type(4))) float f32x4;

typedef const __attribute__((address_space(1))) unsigned int* gAS1;
typedef __attribute__((address_space(3))) unsigned int* lAS3;

// ---- fused fp32->fp16 convert (x, W1, W2) + np-replicating row sum-of-squares
// ---- + Bdeg zeroing (replaces hipMemsetAsync) ----
// R8 lesson (journal): device-scope __threadfence in a 16k-block kernel costs
// ~240us on gfx950 (rescore 394us, all pipes idle) — NO fence-based fusion;
// kernel boundaries are the cheap cross-block ordering primitive here.
#define NXG (NN*HID/4)
#define NWG (HID*HID/4)
#define CVTB ((NXG + 2*NWG)/256)     // 4224 cvt blocks
__global__ __launch_bounds__(256) void prep_kernel(const float* __restrict__ x,
                                                   const float* __restrict__ W1,
                                                   const float* __restrict__ W2,
                                                   _Float16* __restrict__ xh,
                                                   _Float16* __restrict__ W1h,
                                                   _Float16* __restrict__ W2h,
                                                   float* __restrict__ sqf,
                                                   int* __restrict__ Bdeg){
  #pragma clang fp contract(off)
  int b = blockIdx.x;
  int g0 = b * 256 + threadIdx.x;
  if (g0 < NN) Bdeg[g0] = 0;
  if (b < CVTB){
    int g = g0;
    const float* src; _Float16* dst; int o;
    if (g < NXG)            { src = x;  dst = xh;  o = g; }
    else if (g < NXG + NWG) { src = W1; dst = W1h; o = g - NXG; }
    else                    { src = W2; dst = W2h; o = g - NXG - NWG; }
    float4 v = ((const float4*)src)[o];
    f16x4 h; h.x = (_Float16)v.x; h.y = (_Float16)v.y; h.z = (_Float16)v.z; h.w = (_Float16)v.w;
    ((f16x4*)dst)[o] = h;
  } else {
    int bb = b - CVTB;
    int lane = threadIdx.x & 63;
    int rw   = lane >> 4;
    int h    = (lane >> 3) & 1;
    int j    = lane & 7;
    int row  = (bb * 4 + (threadIdx.x >> 6)) * 4 + rw;
    const float* p = x + (size_t)row * HID + h*128 + j;
    float v0 = p[0];
    float r  = v0 * v0;
    #pragma unroll
    for (int i = 1; i < 16; ++i){ float v = p[i*8]; float m = v * v; r = r + m; }
    float t1 = r  + __shfl_xor(r,  1);
    float t2 = t1 + __shfl_xor(t1, 2);
    float t3 = t2 + __shfl_xor(t2, 4);
    float tot = t3 + __shfl_xor(t3, 8);
    if (h == 0 && j == 0) sqf[row] = tot;
  }
}

// stage 64x256 f16 tile into LDS with padded stride (256 threads) — gemm body
__device__ __forceinline__ void load_tile64(unsigned short* dst, const unsigned short* src, int tid){
  const uint4* s = (const uint4*)src;
  #pragma unroll
  for (int r = 0; r < 8; ++r){
    int fl  = tid + (r << 8);
    int row = fl >> 5;
    int c   = fl & 31;
    *(uint4*)&dst[row*LDSK + (c << 3)] = s[fl];
  }
}

// 4-op sorted-ascending top-4 insert (R6-proven):
// b0'=min(k,b0); bN'=med3(k,b(N-1),bN)
__device__ __forceinline__ unsigned umed3(unsigned a, unsigned b, unsigned c){
  unsigned d;
  asm("v_med3_u32 %0, %1, %2, %3" : "=v"(d) : "v"(a), "v"(b), "v"(c));
  return d;
}
__device__ __forceinline__ void ins4(unsigned (&b)[4], unsigned k){
  unsigned b0 = b[0], b1 = b[1], b2 = b[2];
  b[0] = k < b0 ? k : b0;          // v_min_u32
  b[1] = umed3(k, b0, b1);
  b[2] = umed3(k, b1, b2);
  b[3] = umed3(k, b2, b[3]);
}

// fp16 MFMA Gram, swapped operands, FOUR stationary i-sets/wave (R6-proven).
// XOR-swizzled row-major LDS + double-buffered 32-row tiles (R5-proven).
// Packed u32 scan key + VBIAS fold, self dropped in rescore (R3/R4-proven).
// BYTE-IDENTICAL to the R6-verified kernel.
__global__ __launch_bounds__(256, 2) void knn_kernel(const _Float16* __restrict__ xh,
                                                     const float* __restrict__ sqf,
                                                     unsigned* __restrict__ candk){
  __shared__ __align__(16) unsigned short Xj[2][JT*256];  // 2 x 16KB swizzled tiles; aliased as merge buf
  __shared__ __align__(16) float sqj64[2][JT];            // sq_j*64 + VBIAS, double-buffered

  int tid  = threadIdx.x;
  int sl   = blockIdx.x & (NSLICE-1);
  int i0   = (blockIdx.x / NSLICE) * ITILE;
  int jb0  = sl * JSL;
  int wave = tid >> 6, lane = tid & 63, quad = lane >> 4, lcol = lane & 15;

  f16x8 bfr[NSETS][8];
  #pragma unroll
  for (int s = 0; s < NSETS; ++s){
    const _Float16* br = xh + (size_t)(i0 + s*64 + wave*16 + lcol) * HID + quad*8;
    #pragma unroll
    for (int ks = 0; ks < 8; ++ks) bfr[s][ks] = *(const f16x8*)(br + ks*32);
  }

  const _Float16* gsrc[4];
  #pragma unroll
  for (int r = 0; r < 4; ++r){
    int m   = r*256 + tid;
    int row = m >> 5;
    int ch  = m & 31;
    gsrc[r] = xh + (size_t)row * HID + ((ch ^ (row & 7)) << 3);
  }

  int b0 = lcol*512 + ((quad ^ (lcol & 3)) << 4) + (((lcol >> 2) & 1) << 6);
  int b1 = b0 ^ 64;

  unsigned bk[NSETS][4];
  #pragma unroll
  for (int s = 0; s < NSETS; ++s)
    #pragma unroll
    for (int e = 0; e < 4; ++e) bk[s][e] = KEYMAX;

  {
    size_t joff = (size_t)jb0 * HID;
    #pragma unroll
    for (int r = 0; r < 4; ++r)
      __builtin_amdgcn_global_load_lds((gAS1)(const void*)(gsrc[r] + joff),
                                       (lAS3)(void*)&Xj[0][(r*256 + tid) * 8],
                                       16, 0, 0);
    if (tid < JT) sqj64[0][tid] = fmaf(sqf[jb0 + tid], 64.f, VBIAS);
  }
  __syncthreads();

  for (int it = 0; it < NIT; ++it){
    if (it + 1 < NIT){
      int nb = (it + 1) & 1;
      int jn = jb0 + (it + 1) * JT;
      size_t joff = (size_t)jn * HID;
      #pragma unroll
      for (int r = 0; r < 4; ++r)
        __builtin_amdgcn_global_load_lds((gAS1)(const void*)(gsrc[r] + joff),
                                         (lAS3)(void*)&Xj[nb][(r*256 + tid) * 8],
                                         16, 0, 0);
      if (tid < JT) sqj64[nb][tid] = fmaf(sqf[jn + tid], 64.f, VBIAS);
    }

    const char*  tb  = (const char*)&Xj[it & 1][0];
    const float* sjb = sqj64[it & 1];
    int jb = jb0 + it * JT;

    #pragma unroll
    for (int sub = 0; sub < 2; ++sub){
      f32x4 acc[NSETS];
      #pragma unroll
      for (int s = 0; s < NSETS; ++s) acc[s] = (f32x4){0.f,0.f,0.f,0.f};
      #pragma unroll
      for (int ks = 0; ks < 8; ++ks){
        f16x8 a = *(const f16x8*)(tb + sub*8192 + ((ks >> 1) << 7) + ((ks & 1) ? b1 : b0));
        #pragma unroll
        for (int s = 0; s < NSETS; ++s)
          acc[s] = __builtin_amdgcn_mfma_f32_16x16x32_f16(a, bfr[s][ks], acc[s], 0, 0, 0);
      }
      float4 sj4 = *(const float4*)&sjb[sub*16 + quad*4];
      int jbase = jb + sub*16 + quad*4;
      #pragma unroll
      for (int reg = 0; reg < 4; ++reg){
        int gj = jbase + reg;
        float sj = (&sj4.x)[reg];
        #pragma unroll
        for (int s = 0; s < NSETS; ++s){
          float v64 = fmaf(-128.f, acc[s][reg], sj);   // (sj - 2*dot)*64 + VBIAS > 0 always
          unsigned kv = (unsigned)v64;                 // v_cvt_u32_f32
          unsigned key = (kv << 14) + (unsigned)gj;    // v_lshl_add_u32
          ins4(bk[s], key);
        }
      }
    }
    __syncthreads();   // implicit vmcnt(0): drains the prefetch issued ABOVE (old)
  }

  unsigned* Mk = (unsigned*)Xj;            // ITILE x 17 u32 = 17408 B (<= 32768)
  #pragma unroll
  for (int s = 0; s < NSETS; ++s){
    int base = (s*64 + wave*16 + lcol)*MSTRIDE + quad*4;
    #pragma unroll
    for (int e = 0; e < 4; ++e) Mk[base+e] = bk[s][e];
  }
  __syncthreads();
  if (tid < ITILE){
    unsigned fk[4];
    #pragma unroll
    for (int e = 0; e < 4; ++e) fk[e] = KEYMAX;
    #pragma unroll
    for (int s = 0; s < 16; ++s) ins4(fk, Mk[tid*MSTRIDE + s]);
    int g = i0 + tid;
    #pragma unroll
    for (int e = 0; e < 4; ++e)
      candk[(size_t)g*(NSLICE*4) + sl*4 + e] = fk[e];
  }
}

// Rescore (R6-verified, fence-free): mask the self key, rank the 64 packed
// scan keys, take top-8, stage those rows TRANSPOSED in LDS, run the exact
// np-replicating fp32 pipeline: dot = sequential-in-k fp32 FMA chain,
// d2 = fl32(fl32(sq_i+sq_j) - 2*dot). Final rank by (d2, index) lex.
// One wave per node.
__global__ __launch_bounds__(64) void rescore_kernel(const float* __restrict__ x,
                                                     const float* __restrict__ sqf,
                                                     const unsigned* __restrict__ candk,
                                                     int* __restrict__ idx_out,
                                                     int* __restrict__ Bdeg){
  #pragma clang fp contract(off)
  __shared__ float Xi[256];
  __shared__ float Xct[256][NRS+1];   // transposed candidate rows, 9.2 KB
  __shared__ float dex[NRS];
  __shared__ int   sel[NRS];
  int i = blockIdx.x;
  int t = threadIdx.x;            // 0..63
  ((float4*)Xi)[t] = ((const float4*)(x + (size_t)i * HID))[t];
  unsigned kv = candk[(size_t)i*(NSLICE*4) + t];
  if ((kv & 16383u) == (unsigned)i) kv = KEYMAX;   // drop self
  int rank = 0;
  for (int s = 0; s < 64; ++s){
    unsigned ks = __shfl(kv, s);
    rank += (ks < kv) ? 1 : 0;
  }
  if (rank < NRS) sel[rank] = (int)(kv & 16383u);
  __syncthreads();
  {
    int r = t >> 3, seg = t & 7;     // 8 rows x 8 segments
    const float4* src = (const float4*)(x + (size_t)sel[r] * HID);
    #pragma unroll
    for (int m = 0; m < 8; ++m){
      float4 v = src[seg + 8*m];
      int k = 4*(seg + 8*m);
      Xct[k+0][r] = v.x; Xct[k+1][r] = v.y; Xct[k+2][r] = v.z; Xct[k+3][r] = v.w;
    }
  }
  __syncthreads();
  if (t < NRS){
    int j = sel[t];
    float acc = 0.f;
    for (int k = 0; k < 256; ++k) acc = fmaf(Xi[k], Xct[k][t], acc);
    float t1   = sqf[i] + sqf[j];
    float twod = 2.0f * acc;
    dex[t] = t1 - twod;
  }
  __syncthreads();
  if (t == 0){
    unsigned taken = 0;
    #pragma unroll
    for (int k = 0; k < 4; ++k){
      float bdv = FLTMAX; int bj = 0x7fffffff, bs = -1;
      for (int s = 0; s < NRS; ++s){
        if (taken & (1u << s)) continue;
        float d = dex[s]; int j = sel[s];
        if (d < bdv || (d == bdv && j < bj)){ bdv = d; bj = j; bs = s; }
      }
      taken |= 1u << bs;
      idx_out[i*4 + k] = bj;
      atomicAdd(&Bdeg[bj], 1);
    }
  }
}

// out[i][o] = sum_k A[i][k] * W[o][k]   (A: Mx256 f16, W staged f16, out f16)
__global__ __launch_bounds__(256) void gemm_xw(const _Float16* __restrict__ A,
                                               const _Float16* __restrict__ W,
                                               _Float16* __restrict__ out){
  __shared__ unsigned short Ws[64 * LDSK];
  int tid = threadIdx.x;
  int i0 = (blockIdx.x >> 2) * 64;
  int o0 = (blockIdx.x & 3)  * 64;
  int wave = tid >> 6, lane = tid & 63, quad = lane >> 4, lcol = lane & 15;
  load_tile64(Ws, (const unsigned short*)(W + (size_t)o0 * HID), tid);
  f16x8 a[8];
  const _Float16* arow = A + (size_t)(i0 + wave*16 + lcol) * HID + quad*8;
  #pragma unroll
  for (int ks = 0; ks < 8; ++ks) a[ks] = *(const f16x8*)(arow + ks*32);
  __syncthreads();
  #pragma unroll
  for (int sub = 0; sub < 4; ++sub){
    f32x4 acc = {0.f, 0.f, 0.f, 0.f};
    #pragma unroll
    for (int ks = 0; ks < 8; ++ks){
      f16x8 b = *(const f16x8*)&Ws[(sub*16 + lcol)*LDSK + quad*8 + ks*32];
      acc = __builtin_amdgcn_mfma_f32_16x16x32_f16(a[ks], b, acc, 0, 0, 0);
    }
    #pragma unroll
    for (int reg = 0; reg < 4; ++reg)
      out[(size_t)(i0 + wave*16 + quad*4 + reg)*HID + o0 + sub*16 + lcol] = (_Float16)acc[reg];
  }
}

__global__ __launch_bounds__(256) void prefix_kernel(const int* __restrict__ Bdeg,
                                                     int* __restrict__ off,
                                                     int* __restrict__ cursor){
  __shared__ int psum[256];
  __shared__ int excl[256];
  int t = threadIdx.x;
  int base = t * 64;
  int s = 0;
  for (int k = 0; k < 64; ++k) s += Bdeg[base + k];
  psum[t] = s;
  __syncthreads();
  if (t == 0){ int a = 0; for (int k = 0; k < 256; ++k){ excl[k] = a; a += psum[k]; } }
  __syncthreads();
  int a = excl[t];
  for (int k = 0; k < 64; ++k){ int dv = Bdeg[base + k]; off[base+k] = a; cursor[base+k] = a; a += dv; }
}

__global__ __launch_bounds__(256) void fill_kernel(const int* __restrict__ idx,
                                                   int* __restrict__ cursor,
                                                   int* __restrict__ rev){
  int i = blockIdx.x * 256 + threadIdx.x;
  #pragma unroll
  for (int t = 0; t < 4; ++t){
    int e = idx[i*4 + t];
    int p = atomicAdd(&cursor[e], 1);
    rev[p] = i;
  }
}

// E[e] = mean over contributing nodes of xt[node]  (gather via reverse CSR)
__global__ __launch_bounds__(256) void efeat_kernel(const _Float16* __restrict__ xt,
                                                    const int* __restrict__ off,
                                                    const int* __restrict__ deg,
                                                    const int* __restrict__ rev,
                                                    _Float16* __restrict__ E){
  int c = threadIdx.x;
  for (int e = blockIdx.x; e < NN; e += GSB){
    int o = off[e], d = deg[e];
    float s = 0.f;
    for (int k = 0; k < d; ++k) s += (float)xt[(size_t)rev[o + k]*HID + c];
    E[(size_t)e*HID + c] = (_Float16)((d > 0) ? s / (float)d : 0.f);
  }
}

__global__ __launch_bounds__(256) void fin1_kernel(const _Float16* __restrict__ E,
                                                   const int* __restrict__ idx,
                                                   const float* __restrict__ b1,
                                                   const float* __restrict__ pa,
                                                   _Float16* __restrict__ h1){
  int c = threadIdx.x;
  float bc = b1[c];
  float a  = pa[0];
  for (int i = blockIdx.x; i < NN; i += GSB){
    const int* ip = idx + i*4;
    float s = (float)E[(size_t)ip[0]*HID + c] + (float)E[(size_t)ip[1]*HID + c]
            + (float)E[(size_t)ip[2]*HID + c] + (float)E[(size_t)ip[3]*HID + c];
    float acc = 0.25f * s + bc;
    acc = (acc >= 0.f) ? acc : a * acc;
    h1[(size_t)i*HID + c] = (_Float16)acc;
  }
}

__global__ __launch_bounds__(256) void fin2_kernel(const _Float16* __restrict__ E,
                                                   const int* __restrict__ idx,
                                                   const float* __restrict__ b2,
                                                   const float* __restrict__ x,
                                                   const float* __restrict__ pa,
                                                   float* __restrict__ out){
  int c = threadIdx.x;
  float bc = b2[c];
  float a  = pa[0];
  for (int i = blockIdx.x; i < NN; i += GSB){
    const int* ip = idx + i*4;
    float s = (float)E[(size_t)ip[0]*HID + c] + (float)E[(size_t)ip[1]*HID + c]
            + (float)E[(size_t)ip[2]*HID + c] + (float)E[(size_t)ip[3]*HID + c];
    float acc = 0.25f * s + bc + x[(size_t)i*HID + c];
    acc = (acc >= 0.f) ? acc : a * acc;
    out[(size_t)i*HID + c] = acc;
  }
}

extern "C" void kernel_launch(void* const* d_in, const int* in_sizes, int n_in,
                              void* d_out, int out_size, void* d_ws, size_t ws_size,
                              hipStream_t stream){
  (void)in_sizes; (void)n_in; (void)out_size; (void)ws_size;
  const float* x  = (const float*)d_in[0];
  // d_in[1] = edge_index (int32), unused by the math
  const float* W1 = (const float*)d_in[2];
  const float* b1 = (const float*)d_in[3];
  const float* W2 = (const float*)d_in[4];
  const float* b2 = (const float*)d_in[5];
  const float* pa = (const float*)d_in[6];
  float* out = (float*)d_out;

  char* ws = (char*)d_ws;
  float*  sqf    = (float*) (ws + 0);                        //  64 KB
  int*    idx    = (int*)   (ws + 65536);                    // 256 KB
  int*    Bdeg   = (int*)   (ws + 327680);                   //  64 KB
  int*    offE   = (int*)   (ws + 393216);                   //  64 KB
  int*    cursor = (int*)   (ws + 458752);                   //  64 KB
  int*    rev    = (int*)   (ws + 524288);                   // 256 KB
  _Float16* xh   = (_Float16*)(ws + (size_t)(5<<20));        //   8 MB
  _Float16* W1h  = (_Float16*)(ws + (size_t)(13<<20));       // 128 KB
  _Float16* W2h  = (_Float16*)(ws + (size_t)(13<<20) + 131072);
  _Float16* xt   = (_Float16*)(ws + (size_t)(13<<20) + 262144);            // 8 MB
  _Float16* E    = (_Float16*)(ws + (size_t)(21<<20) + 262144);            // 8 MB
  _Float16* h1   = (_Float16*)(ws + (size_t)(29<<20) + 262144);            // 8 MB
  // candk (NN*64*4B = 4 MB) aliases the xt region: dead until the first
  // gemm_xw (which runs after rescore consumed it) -> no ws growth.
  unsigned* candk = (unsigned*)xt;                           // 4 MB

  prep_kernel   <<<CVTB + NN/16, 256, 0, stream>>>(x, W1, W2, xh, W1h, W2h, sqf, Bdeg);
  knn_kernel    <<<(NN/ITILE)*NSLICE, 256, 0, stream>>>(xh, sqf, candk);
  rescore_kernel<<<NN, 64, 0, stream>>>(x, sqf, candk, idx, Bdeg);
  prefix_kernel <<<1, 256, 0, stream>>>(Bdeg, offE, cursor);
  fill_kernel   <<<NN/256, 256, 0, stream>>>(idx, cursor, rev);

  gemm_xw       <<<(NN/64)*4, 256, 0, stream>>>(xh, W1h, xt);
  efeat_kernel  <<<GSB, 256, 0, stream>>>(xt, offE, Bdeg, rev, E);
  fin1_kernel   <<<GSB, 256, 0, stream>>>(E, idx, b1, pa, h1);

  gemm_xw       <<<(NN/64)*4, 256, 0, stream>>>(h1, W2h, xt);
  efeat_kernel  <<<GSB, 256, 0, stream>>>(xt, offE, Bdeg, rev, E);
  fin2_kernel   <<<GSB, 256, 0, stream>>>(E, idx, b2, x, pa, out);
}

// Round 10
// 571.485 us; speedup vs baseline: 1.5720x; 1.0023x over previous
//
#include <hip/hip_runtime.h>
#include <stdint.h>

#define NN   16384
#define HID  256
#define LDSK 264            // padded LDS row stride in f16 elems (gemm body)
#define NSLICE 16           // j sliced 16-way
#define JSL  (NN/NSLICE)    // 1024 j's per slice
#define JT   32             // j-tile rows, 16KB tiles, double-buffered (R5-proven)
#define NIT  (JSL/JT)       // 32 iterations per block
#define NSETS 4             // R6-proven: LDS bytes/eval halved, no spill at (256,2)
#define ITILE (NSETS*64)    // 256 i's per block
#define NRS  8              // exact-rescore chains (top-8 of 64 by scan key)
#define GSB  2048           // grid-stride block count for efeat/fin
#define FLTMAX 3.402823466e38f
#define KEYMAX 0xFFFFFFFFu
#define VBIAS 131072.0f     // folded into sqj64; keeps v64+B > 0 for ALL pairs incl. self
#define MSTRIDE 17          // padded merge stride (u32): tid*17 reads are conflict-free

typedef __attribute__((ext_vector_type(8))) _Float16 f16x8;
typedef __attribute__((ext_vector_type(4))) _Float16 f16x4;
typedef __attribute__((ext_vector_type(4))) float f32x4;

typedef const __attribute__((address_space(1))) unsigned int* gAS1;
typedef __attribute__((address_space(3))) unsigned int* lAS3;

// ---- fused fp32->fp16 convert (x, W1, W2) + np-replicating row sum-of-squares
// ---- + Bdeg zeroing (replaces hipMemsetAsync) ----
// R8 lesson (journal): device-scope __threadfence in a 16k-block kernel costs
// ~240us on gfx950 — NO fence-based fusion; kernel boundaries are the cheap
// cross-block ordering primitive here.
// R9 accounting (journal): knn 161 / rescore ~65 (R8 subtraction) / unknown
// residual ~340. R10 splits knn in two dispatches to drop the rocprof top-5
// visibility threshold from 161us to ~81us — performance-neutral (1024 blocks
// already ran as 2 sequential 2-blocks/CU rounds).
#define NXG (NN*HID/4)
#define NWG (HID*HID/4)
#define CVTB ((NXG + 2*NWG)/256)     // 4224 cvt blocks
__global__ __launch_bounds__(256) void prep_kernel(const float* __restrict__ x,
                                                   const float* __restrict__ W1,
                                                   const float* __restrict__ W2,
                                                   _Float16* __restrict__ xh,
                                                   _Float16* __restrict__ W1h,
                                                   _Float16* __restrict__ W2h,
                                                   float* __restrict__ sqf,
                                                   int* __restrict__ Bdeg){
  #pragma clang fp contract(off)
  int b = blockIdx.x;
  int g0 = b * 256 + threadIdx.x;
  if (g0 < NN) Bdeg[g0] = 0;
  if (b < CVTB){
    int g = g0;
    const float* src; _Float16* dst; int o;
    if (g < NXG)            { src = x;  dst = xh;  o = g; }
    else if (g < NXG + NWG) { src = W1; dst = W1h; o = g - NXG; }
    else                    { src = W2; dst = W2h; o = g - NXG - NWG; }
    float4 v = ((const float4*)src)[o];
    f16x4 h; h.x = (_Float16)v.x; h.y = (_Float16)v.y; h.z = (_Float16)v.z; h.w = (_Float16)v.w;
    ((f16x4*)dst)[o] = h;
  } else {
    int bb = b - CVTB;
    int lane = threadIdx.x & 63;
    int rw   = lane >> 4;
    int h    = (lane >> 3) & 1;
    int j    = lane & 7;
    int row  = (bb * 4 + (threadIdx.x >> 6)) * 4 + rw;
    const float* p = x + (size_t)row * HID + h*128 + j;
    float v0 = p[0];
    float r  = v0 * v0;
    #pragma unroll
    for (int i = 1; i < 16; ++i){ float v = p[i*8]; float m = v * v; r = r + m; }
    float t1 = r  + __shfl_xor(r,  1);
    float t2 = t1 + __shfl_xor(t1, 2);
    float t3 = t2 + __shfl_xor(t2, 4);
    float tot = t3 + __shfl_xor(t3, 8);
    if (h == 0 && j == 0) sqf[row] = tot;
  }
}

// stage 64x256 f16 tile into LDS with padded stride (256 threads) — gemm body
__device__ __forceinline__ void load_tile64(unsigned short* dst, const unsigned short* src, int tid){
  const uint4* s = (const uint4*)src;
  #pragma unroll
  for (int r = 0; r < 8; ++r){
    int fl  = tid + (r << 8);
    int row = fl >> 5;
    int c   = fl & 31;
    *(uint4*)&dst[row*LDSK + (c << 3)] = s[fl];
  }
}

// 4-op sorted-ascending top-4 insert (R6-proven):
// b0'=min(k,b0); bN'=med3(k,b(N-1),bN)
__device__ __forceinline__ unsigned umed3(unsigned a, unsigned b, unsigned c){
  unsigned d;
  asm("v_med3_u32 %0, %1, %2, %3" : "=v"(d) : "v"(a), "v"(b), "v"(c));
  return d;
}
__device__ __forceinline__ void ins4(unsigned (&b)[4], unsigned k){
  unsigned b0 = b[0], b1 = b[1], b2 = b[2];
  b[0] = k < b0 ? k : b0;          // v_min_u32
  b[1] = umed3(k, b0, b1);
  b[2] = umed3(k, b1, b2);
  b[3] = umed3(k, b2, b[3]);
}

// fp16 MFMA Gram, swapped operands, FOUR stationary i-sets/wave (R6-proven).
// XOR-swizzled row-major LDS + double-buffered 32-row tiles (R5-proven).
// Packed u32 scan key + VBIAS fold, self dropped in rescore (R3/R4-proven).
// R10: ibase param — kernel launched twice over i-halves (diagnostic split).
__global__ __launch_bounds__(256, 2) void knn_kernel(const _Float16* __restrict__ xh,
                                                     const float* __restrict__ sqf,
                                                     unsigned* __restrict__ candk,
                                                     int ibase){
  __shared__ __align__(16) unsigned short Xj[2][JT*256];  // 2 x 16KB swizzled tiles; aliased as merge buf
  __shared__ __align__(16) float sqj64[2][JT];            // sq_j*64 + VBIAS, double-buffered

  int tid  = threadIdx.x;
  int sl   = blockIdx.x & (NSLICE-1);
  int i0   = ibase + (blockIdx.x / NSLICE) * ITILE;
  int jb0  = sl * JSL;
  int wave = tid >> 6, lane = tid & 63, quad = lane >> 4, lcol = lane & 15;

  f16x8 bfr[NSETS][8];
  #pragma unroll
  for (int s = 0; s < NSETS; ++s){
    const _Float16* br = xh + (size_t)(i0 + s*64 + wave*16 + lcol) * HID + quad*8;
    #pragma unroll
    for (int ks = 0; ks < 8; ++ks) bfr[s][ks] = *(const f16x8*)(br + ks*32);
  }

  const _Float16* gsrc[4];
  #pragma unroll
  for (int r = 0; r < 4; ++r){
    int m   = r*256 + tid;
    int row = m >> 5;
    int ch  = m & 31;
    gsrc[r] = xh + (size_t)row * HID + ((ch ^ (row & 7)) << 3);
  }

  int b0 = lcol*512 + ((quad ^ (lcol & 3)) << 4) + (((lcol >> 2) & 1) << 6);
  int b1 = b0 ^ 64;

  unsigned bk[NSETS][4];
  #pragma unroll
  for (int s = 0; s < NSETS; ++s)
    #pragma unroll
    for (int e = 0; e < 4; ++e) bk[s][e] = KEYMAX;

  {
    size_t joff = (size_t)jb0 * HID;
    #pragma unroll
    for (int r = 0; r < 4; ++r)
      __builtin_amdgcn_global_load_lds((gAS1)(const void*)(gsrc[r] + joff),
                                       (lAS3)(void*)&Xj[0][(r*256 + tid) * 8],
                                       16, 0, 0);
    if (tid < JT) sqj64[0][tid] = fmaf(sqf[jb0 + tid], 64.f, VBIAS);
  }
  __syncthreads();

  for (int it = 0; it < NIT; ++it){
    if (it + 1 < NIT){
      int nb = (it + 1) & 1;
      int jn = jb0 + (it + 1) * JT;
      size_t joff = (size_t)jn * HID;
      #pragma unroll
      for (int r = 0; r < 4; ++r)
        __builtin_amdgcn_global_load_lds((gAS1)(const void*)(gsrc[r] + joff),
                                         (lAS3)(void*)&Xj[nb][(r*256 + tid) * 8],
                                         16, 0, 0);
      if (tid < JT) sqj64[nb][tid] = fmaf(sqf[jn + tid], 64.f, VBIAS);
    }

    const char*  tb  = (const char*)&Xj[it & 1][0];
    const float* sjb = sqj64[it & 1];
    int jb = jb0 + it * JT;

    #pragma unroll
    for (int sub = 0; sub < 2; ++sub){
      f32x4 acc[NSETS];
      #pragma unroll
      for (int s = 0; s < NSETS; ++s) acc[s] = (f32x4){0.f,0.f,0.f,0.f};
      #pragma unroll
      for (int ks = 0; ks < 8; ++ks){
        f16x8 a = *(const f16x8*)(tb + sub*8192 + ((ks >> 1) << 7) + ((ks & 1) ? b1 : b0));
        #pragma unroll
        for (int s = 0; s < NSETS; ++s)
          acc[s] = __builtin_amdgcn_mfma_f32_16x16x32_f16(a, bfr[s][ks], acc[s], 0, 0, 0);
      }
      float4 sj4 = *(const float4*)&sjb[sub*16 + quad*4];
      int jbase = jb + sub*16 + quad*4;
      #pragma unroll
      for (int reg = 0; reg < 4; ++reg){
        int gj = jbase + reg;
        float sj = (&sj4.x)[reg];
        #pragma unroll
        for (int s = 0; s < NSETS; ++s){
          float v64 = fmaf(-128.f, acc[s][reg], sj);   // (sj - 2*dot)*64 + VBIAS > 0 always
          unsigned kv = (unsigned)v64;                 // v_cvt_u32_f32
          unsigned key = (kv << 14) + (unsigned)gj;    // v_lshl_add_u32
          ins4(bk[s], key);
        }
      }
    }
    __syncthreads();   // implicit vmcnt(0): drains the prefetch issued ABOVE (old)
  }

  unsigned* Mk = (unsigned*)Xj;            // ITILE x 17 u32 = 17408 B (<= 32768)
  #pragma unroll
  for (int s = 0; s < NSETS; ++s){
    int base = (s*64 + wave*16 + lcol)*MSTRIDE + quad*4;
    #pragma unroll
    for (int e = 0; e < 4; ++e) Mk[base+e] = bk[s][e];
  }
  __syncthreads();
  if (tid < ITILE){
    unsigned fk[4];
    #pragma unroll
    for (int e = 0; e < 4; ++e) fk[e] = KEYMAX;
    #pragma unroll
    for (int s = 0; s < 16; ++s) ins4(fk, Mk[tid*MSTRIDE + s]);
    int g = i0 + tid;
    #pragma unroll
    for (int e = 0; e < 4; ++e)
      candk[(size_t)g*(NSLICE*4) + sl*4 + e] = fk[e];
  }
}

// Rescore (R6-verified, fence-free): mask the self key, rank the 64 packed
// scan keys, take top-8, stage those rows TRANSPOSED in LDS, run the exact
// np-replicating fp32 pipeline: dot = sequential-in-k fp32 FMA chain,
// d2 = fl32(fl32(sq_i+sq_j) - 2*dot). Final rank by (d2, index) lex.
// One wave per node.
__global__ __launch_bounds__(64) void rescore_kernel(const float* __restrict__ x,
                                                     const float* __restrict__ sqf,
                                                     const unsigned* __restrict__ candk,
                                                     int* __restrict__ idx_out,
                                                     int* __restrict__ Bdeg){
  #pragma clang fp contract(off)
  __shared__ float Xi[256];
  __shared__ float Xct[256][NRS+1];   // transposed candidate rows, 9.2 KB
  __shared__ float dex[NRS];
  __shared__ int   sel[NRS];
  int i = blockIdx.x;
  int t = threadIdx.x;            // 0..63
  ((float4*)Xi)[t] = ((const float4*)(x + (size_t)i * HID))[t];
  unsigned kv = candk[(size_t)i*(NSLICE*4) + t];
  if ((kv & 16383u) == (unsigned)i) kv = KEYMAX;   // drop self
  int rank = 0;
  for (int s = 0; s < 64; ++s){
    unsigned ks = __shfl(kv, s);
    rank += (ks < kv) ? 1 : 0;
  }
  if (rank < NRS) sel[rank] = (int)(kv & 16383u);
  __syncthreads();
  {
    int r = t >> 3, seg = t & 7;     // 8 rows x 8 segments
    const float4* src = (const float4*)(x + (size_t)sel[r] * HID);
    #pragma unroll
    for (int m = 0; m < 8; ++m){
      float4 v = src[seg + 8*m];
      int k = 4*(seg + 8*m);
      Xct[k+0][r] = v.x; Xct[k+1][r] = v.y; Xct[k+2][r] = v.z; Xct[k+3][r] = v.w;
    }
  }
  __syncthreads();
  if (t < NRS){
    int j = sel[t];
    float acc = 0.f;
    for (int k = 0; k < 256; ++k) acc = fmaf(Xi[k], Xct[k][t], acc);
    float t1   = sqf[i] + sqf[j];
    float twod = 2.0f * acc;
    dex[t] = t1 - twod;
  }
  __syncthreads();
  if (t == 0){
    unsigned taken = 0;
    #pragma unroll
    for (int k = 0; k < 4; ++k){
      float bdv = FLTMAX; int bj = 0x7fffffff, bs = -1;
      for (int s = 0; s < NRS; ++s){
        if (taken & (1u << s)) continue;
        float d = dex[s]; int j = sel[s];
        if (d < bdv || (d == bdv && j < bj)){ bdv = d; bj = j; bs = s; }
      }
      taken |= 1u << bs;
      idx_out[i*4 + k] = bj;
      atomicAdd(&Bdeg[bj], 1);
    }
  }
}

// out[i][o] = sum_k A[i][k] * W[o][k]   (A: Mx256 f16, W staged f16, out f16)
__global__ __launch_bounds__(256) void gemm_xw(const _Float16* __restrict__ A,
                                               const _Float16* __restrict__ W,
                                               _Float16* __restrict__ out){
  __shared__ unsigned short Ws[64 * LDSK];
  int tid = threadIdx.x;
  int i0 = (blockIdx.x >> 2) * 64;
  int o0 = (blockIdx.x & 3)  * 64;
  int wave = tid >> 6, lane = tid & 63, quad = lane >> 4, lcol = lane & 15;
  load_tile64(Ws, (const unsigned short*)(W + (size_t)o0 * HID), tid);
  f16x8 a[8];
  const _Float16* arow = A + (size_t)(i0 + wave*16 + lcol) * HID + quad*8;
  #pragma unroll
  for (int ks = 0; ks < 8; ++ks) a[ks] = *(const f16x8*)(arow + ks*32);
  __syncthreads();
  #pragma unroll
  for (int sub = 0; sub < 4; ++sub){
    f32x4 acc = {0.f, 0.f, 0.f, 0.f};
    #pragma unroll
    for (int ks = 0; ks < 8; ++ks){
      f16x8 b = *(const f16x8*)&Ws[(sub*16 + lcol)*LDSK + quad*8 + ks*32];
      acc = __builtin_amdgcn_mfma_f32_16x16x32_f16(a[ks], b, acc, 0, 0, 0);
    }
    #pragma unroll
    for (int reg = 0; reg < 4; ++reg)
      out[(size_t)(i0 + wave*16 + quad*4 + reg)*HID + o0 + sub*16 + lcol] = (_Float16)acc[reg];
  }
}

__global__ __launch_bounds__(256) void prefix_kernel(const int* __restrict__ Bdeg,
                                                     int* __restrict__ off,
                                                     int* __restrict__ cursor){
  __shared__ int psum[256];
  __shared__ int excl[256];
  int t = threadIdx.x;
  int base = t * 64;
  int s = 0;
  for (int k = 0; k < 64; ++k) s += Bdeg[base + k];
  psum[t] = s;
  __syncthreads();
  if (t == 0){ int a = 0; for (int k = 0; k < 256; ++k){ excl[k] = a; a += psum[k]; } }
  __syncthreads();
  int a = excl[t];
  for (int k = 0; k < 64; ++k){ int dv = Bdeg[base + k]; off[base+k] = a; cursor[base+k] = a; a += dv; }
}

__global__ __launch_bounds__(256) void fill_kernel(const int* __restrict__ idx,
                                                   int* __restrict__ cursor,
                                                   int* __restrict__ rev){
  int i = blockIdx.x * 256 + threadIdx.x;
  #pragma unroll
  for (int t = 0; t < 4; ++t){
    int e = idx[i*4 + t];
    int p = atomicAdd(&cursor[e], 1);
    rev[p] = i;
  }
}

// E[e] = mean over contributing nodes of xt[node]  (gather via reverse CSR)
__global__ __launch_bounds__(256) void efeat_kernel(const _Float16* __restrict__ xt,
                                                    const int* __restrict__ off,
                                                    const int* __restrict__ deg,
                                                    const int* __restrict__ rev,
                                                    _Float16* __restrict__ E){
  int c = threadIdx.x;
  for (int e = blockIdx.x; e < NN; e += GSB){
    int o = off[e], d = deg[e];
    float s = 0.f;
    for (int k = 0; k < d; ++k) s += (float)xt[(size_t)rev[o + k]*HID + c];
    E[(size_t)e*HID + c] = (_Float16)((d > 0) ? s / (float)d : 0.f);
  }
}

__global__ __launch_bounds__(256) void fin1_kernel(const _Float16* __restrict__ E,
                                                   const int* __restrict__ idx,
                                                   const float* __restrict__ b1,
                                                   const float* __restrict__ pa,
                                                   _Float16* __restrict__ h1){
  int c = threadIdx.x;
  float bc = b1[c];
  float a  = pa[0];
  for (int i = blockIdx.x; i < NN; i += GSB){
    const int* ip = idx + i*4;
    float s = (float)E[(size_t)ip[0]*HID + c] + (float)E[(size_t)ip[1]*HID + c]
            + (float)E[(size_t)ip[2]*HID + c] + (float)E[(size_t)ip[3]*HID + c];
    float acc = 0.25f * s + bc;
    acc = (acc >= 0.f) ? acc : a * acc;
    h1[(size_t)i*HID + c] = (_Float16)acc;
  }
}

__global__ __launch_bounds__(256) void fin2_kernel(const _Float16* __restrict__ E,
                                                   const int* __restrict__ idx,
                                                   const float* __restrict__ b2,
                                                   const float* __restrict__ x,
                                                   const float* __restrict__ pa,
                                                   float* __restrict__ out){
  int c = threadIdx.x;
  float bc = b2[c];
  float a  = pa[0];
  for (int i = blockIdx.x; i < NN; i += GSB){
    const int* ip = idx + i*4;
    float s = (float)E[(size_t)ip[0]*HID + c] + (float)E[(size_t)ip[1]*HID + c]
            + (float)E[(size_t)ip[2]*HID + c] + (float)E[(size_t)ip[3]*HID + c];
    float acc = 0.25f * s + bc + x[(size_t)i*HID + c];
    acc = (acc >= 0.f) ? acc : a * acc;
    out[(size_t)i*HID + c] = acc;
  }
}

extern "C" void kernel_launch(void* const* d_in, const int* in_sizes, int n_in,
                              void* d_out, int out_size, void* d_ws, size_t ws_size,
                              hipStream_t stream){
  (void)in_sizes; (void)n_in; (void)out_size; (void)ws_size;
  const float* x  = (const float*)d_in[0];
  // d_in[1] = edge_index (int32), unused by the math
  const float* W1 = (const float*)d_in[2];
  const float* b1 = (const float*)d_in[3];
  const float* W2 = (const float*)d_in[4];
  const float* b2 = (const float*)d_in[5];
  const float* pa = (const float*)d_in[6];
  float* out = (float*)d_out;

  char* ws = (char*)d_ws;
  float*  sqf    = (float*) (ws + 0);                        //  64 KB
  int*    idx    = (int*)   (ws + 65536);                    // 256 KB
  int*    Bdeg   = (int*)   (ws + 327680);                   //  64 KB
  int*    offE   = (int*)   (ws + 393216);                   //  64 KB
  int*    cursor = (int*)   (ws + 458752);                   //  64 KB
  int*    rev    = (int*)   (ws + 524288);                   // 256 KB
  _Float16* xh   = (_Float16*)(ws + (size_t)(5<<20));        //   8 MB
  _Float16* W1h  = (_Float16*)(ws + (size_t)(13<<20));       // 128 KB
  _Float16* W2h  = (_Float16*)(ws + (size_t)(13<<20) + 131072);
  _Float16* xt   = (_Float16*)(ws + (size_t)(13<<20) + 262144);            // 8 MB
  _Float16* E    = (_Float16*)(ws + (size_t)(21<<20) + 262144);            // 8 MB
  _Float16* h1   = (_Float16*)(ws + (size_t)(29<<20) + 262144);            // 8 MB
  // candk (NN*64*4B = 4 MB) aliases the xt region: dead until the first
  // gemm_xw (which runs after rescore consumed it) -> no ws growth.
  unsigned* candk = (unsigned*)xt;                           // 4 MB

  prep_kernel   <<<CVTB + NN/16, 256, 0, stream>>>(x, W1, W2, xh, W1h, W2h, sqf, Bdeg);
  knn_kernel    <<<(NN/ITILE/2)*NSLICE, 256, 0, stream>>>(xh, sqf, candk, 0);
  knn_kernel    <<<(NN/ITILE/2)*NSLICE, 256, 0, stream>>>(xh, sqf, candk, NN/2);
  rescore_kernel<<<NN, 64, 0, stream>>>(x, sqf, candk, idx, Bdeg);
  prefix_kernel <<<1, 256, 0, stream>>>(Bdeg, offE, cursor);
  fill_kernel   <<<NN/256, 256, 0, stream>>>(idx, cursor, rev);

  gemm_xw       <<<(NN/64)*4, 256, 0, stream>>>(xh, W1h, xt);
  efeat_kernel  <<<GSB, 256, 0, stream>>>(xt, offE, Bdeg, rev, E);
  fin1_kernel   <<<GSB, 256, 0, stream>>>(E, idx, b1, pa, h1);

  gemm_xw       <<<(NN/64)*4, 256, 0, stream>>>(h1, W2h, xt);
  efeat_kernel  <<<GSB, 256, 0, stream>>>(xt, offE, Bdeg, rev, E);
  fin2_kernel   <<<GSB, 256, 0, stream>>>(E, idx, b2, x, pa, out);
}

// Round 11
// 451.411 us; speedup vs baseline: 1.9901x; 1.2660x over previous
//
#include <hip/hip_runtime.h>
#include <stdint.h>

#define NN   16384
#define HID  256
#define LDSK 264            // padded LDS row stride in f16 elems (gemm body)
#define NSLICE 16           // j sliced 16-way
#define JSL  (NN/NSLICE)    // 1024 j's per slice
#define JT   32             // j-tile rows, 16KB tiles, double-buffered (R5-proven)
#define NIT  (JSL/JT)       // 32 iterations per block
#define NSETS 4             // R6-proven: LDS bytes/eval halved, no spill at (256,2)
#define ITILE (NSETS*64)    // 256 i's per block
#define NRS  8              // exact-rescore chains (top-8 of 64 by scan key)
#define GSB  2048           // grid-stride block count for efeat/fin
#define NWV  (GSB*4)        // 8192 concurrent waves for wave-per-item kernels
#define FLTMAX 3.402823466e38f
#define KEYMAX 0xFFFFFFFFu
#define VBIAS 131072.0f     // folded into sqj64; keeps v64+B > 0 for ALL pairs incl. self
#define MSTRIDE 17          // padded merge stride (u32): tid*17 reads are conflict-free

typedef __attribute__((ext_vector_type(8))) _Float16 f16x8;
typedef __attribute__((ext_vector_type(4))) _Float16 f16x4;
typedef __attribute__((ext_vector_type(4))) float f32x4;

typedef const __attribute__((address_space(1))) unsigned int* gAS1;
typedef __attribute__((address_space(3))) unsigned int* lAS3;

// ---- fused fp32->fp16 convert (x, W1, W2) + np-replicating row sum-of-squares
// ---- + Bdeg zeroing (replaces hipMemsetAsync) ----
// R8 lesson (journal): device-scope __threadfence in a 16k-block kernel costs
// ~240us on gfx950 — NO fence-based fusion; kernel boundaries are the cheap
// cross-block ordering primitive here.
// R10 finding (journal): efeat was 131us x2 with VALUBusy 1.6%, occupancy 8.8%
// — latency-starved serial gather at 2B/lane. R11 rewrites the three gather
// kernels wave-per-item with f16x4 row vectors (Guideline 13) + unroll-4 ILP.
#define NXG (NN*HID/4)
#define NWG (HID*HID/4)
#define CVTB ((NXG + 2*NWG)/256)     // 4224 cvt blocks
__global__ __launch_bounds__(256) void prep_kernel(const float* __restrict__ x,
                                                   const float* __restrict__ W1,
                                                   const float* __restrict__ W2,
                                                   _Float16* __restrict__ xh,
                                                   _Float16* __restrict__ W1h,
                                                   _Float16* __restrict__ W2h,
                                                   float* __restrict__ sqf,
                                                   int* __restrict__ Bdeg){
  #pragma clang fp contract(off)
  int b = blockIdx.x;
  int g0 = b * 256 + threadIdx.x;
  if (g0 < NN) Bdeg[g0] = 0;
  if (b < CVTB){
    int g = g0;
    const float* src; _Float16* dst; int o;
    if (g < NXG)            { src = x;  dst = xh;  o = g; }
    else if (g < NXG + NWG) { src = W1; dst = W1h; o = g - NXG; }
    else                    { src = W2; dst = W2h; o = g - NXG - NWG; }
    float4 v = ((const float4*)src)[o];
    f16x4 h; h.x = (_Float16)v.x; h.y = (_Float16)v.y; h.z = (_Float16)v.z; h.w = (_Float16)v.w;
    ((f16x4*)dst)[o] = h;
  } else {
    int bb = b - CVTB;
    int lane = threadIdx.x & 63;
    int rw   = lane >> 4;
    int h    = (lane >> 3) & 1;
    int j    = lane & 7;
    int row  = (bb * 4 + (threadIdx.x >> 6)) * 4 + rw;
    const float* p = x + (size_t)row * HID + h*128 + j;
    float v0 = p[0];
    float r  = v0 * v0;
    #pragma unroll
    for (int i = 1; i < 16; ++i){ float v = p[i*8]; float m = v * v; r = r + m; }
    float t1 = r  + __shfl_xor(r,  1);
    float t2 = t1 + __shfl_xor(t1, 2);
    float t3 = t2 + __shfl_xor(t2, 4);
    float tot = t3 + __shfl_xor(t3, 8);
    if (h == 0 && j == 0) sqf[row] = tot;
  }
}

// stage 64x256 f16 tile into LDS with padded stride (256 threads) — gemm body
__device__ __forceinline__ void load_tile64(unsigned short* dst, const unsigned short* src, int tid){
  const uint4* s = (const uint4*)src;
  #pragma unroll
  for (int r = 0; r < 8; ++r){
    int fl  = tid + (r << 8);
    int row = fl >> 5;
    int c   = fl & 31;
    *(uint4*)&dst[row*LDSK + (c << 3)] = s[fl];
  }
}

// 4-op sorted-ascending top-4 insert (R6-proven):
// b0'=min(k,b0); bN'=med3(k,b(N-1),bN)
__device__ __forceinline__ unsigned umed3(unsigned a, unsigned b, unsigned c){
  unsigned d;
  asm("v_med3_u32 %0, %1, %2, %3" : "=v"(d) : "v"(a), "v"(b), "v"(c));
  return d;
}
__device__ __forceinline__ void ins4(unsigned (&b)[4], unsigned k){
  unsigned b0 = b[0], b1 = b[1], b2 = b[2];
  b[0] = k < b0 ? k : b0;          // v_min_u32
  b[1] = umed3(k, b0, b1);
  b[2] = umed3(k, b1, b2);
  b[3] = umed3(k, b2, b[3]);
}

// fp16 MFMA Gram, swapped operands, FOUR stationary i-sets/wave (R6-proven).
// XOR-swizzled row-major LDS + double-buffered 32-row tiles (R5-proven).
// Packed u32 scan key + VBIAS fold, self dropped in rescore (R3/R4-proven).
// Launched twice over i-halves (R10 diagnostic split, perf-neutral).
__global__ __launch_bounds__(256, 2) void knn_kernel(const _Float16* __restrict__ xh,
                                                     const float* __restrict__ sqf,
                                                     unsigned* __restrict__ candk,
                                                     int ibase){
  __shared__ __align__(16) unsigned short Xj[2][JT*256];  // 2 x 16KB swizzled tiles; aliased as merge buf
  __shared__ __align__(16) float sqj64[2][JT];            // sq_j*64 + VBIAS, double-buffered

  int tid  = threadIdx.x;
  int sl   = blockIdx.x & (NSLICE-1);
  int i0   = ibase + (blockIdx.x / NSLICE) * ITILE;
  int jb0  = sl * JSL;
  int wave = tid >> 6, lane = tid & 63, quad = lane >> 4, lcol = lane & 15;

  f16x8 bfr[NSETS][8];
  #pragma unroll
  for (int s = 0; s < NSETS; ++s){
    const _Float16* br = xh + (size_t)(i0 + s*64 + wave*16 + lcol) * HID + quad*8;
    #pragma unroll
    for (int ks = 0; ks < 8; ++ks) bfr[s][ks] = *(const f16x8*)(br + ks*32);
  }

  const _Float16* gsrc[4];
  #pragma unroll
  for (int r = 0; r < 4; ++r){
    int m   = r*256 + tid;
    int row = m >> 5;
    int ch  = m & 31;
    gsrc[r] = xh + (size_t)row * HID + ((ch ^ (row & 7)) << 3);
  }

  int b0 = lcol*512 + ((quad ^ (lcol & 3)) << 4) + (((lcol >> 2) & 1) << 6);
  int b1 = b0 ^ 64;

  unsigned bk[NSETS][4];
  #pragma unroll
  for (int s = 0; s < NSETS; ++s)
    #pragma unroll
    for (int e = 0; e < 4; ++e) bk[s][e] = KEYMAX;

  {
    size_t joff = (size_t)jb0 * HID;
    #pragma unroll
    for (int r = 0; r < 4; ++r)
      __builtin_amdgcn_global_load_lds((gAS1)(const void*)(gsrc[r] + joff),
                                       (lAS3)(void*)&Xj[0][(r*256 + tid) * 8],
                                       16, 0, 0);
    if (tid < JT) sqj64[0][tid] = fmaf(sqf[jb0 + tid], 64.f, VBIAS);
  }
  __syncthreads();

  for (int it = 0; it < NIT; ++it){
    if (it + 1 < NIT){
      int nb = (it + 1) & 1;
      int jn = jb0 + (it + 1) * JT;
      size_t joff = (size_t)jn * HID;
      #pragma unroll
      for (int r = 0; r < 4; ++r)
        __builtin_amdgcn_global_load_lds((gAS1)(const void*)(gsrc[r] + joff),
                                         (lAS3)(void*)&Xj[nb][(r*256 + tid) * 8],
                                         16, 0, 0);
      if (tid < JT) sqj64[nb][tid] = fmaf(sqf[jn + tid], 64.f, VBIAS);
    }

    const char*  tb  = (const char*)&Xj[it & 1][0];
    const float* sjb = sqj64[it & 1];
    int jb = jb0 + it * JT;

    #pragma unroll
    for (int sub = 0; sub < 2; ++sub){
      f32x4 acc[NSETS];
      #pragma unroll
      for (int s = 0; s < NSETS; ++s) acc[s] = (f32x4){0.f,0.f,0.f,0.f};
      #pragma unroll
      for (int ks = 0; ks < 8; ++ks){
        f16x8 a = *(const f16x8*)(tb + sub*8192 + ((ks >> 1) << 7) + ((ks & 1) ? b1 : b0));
        #pragma unroll
        for (int s = 0; s < NSETS; ++s)
          acc[s] = __builtin_amdgcn_mfma_f32_16x16x32_f16(a, bfr[s][ks], acc[s], 0, 0, 0);
      }
      float4 sj4 = *(const float4*)&sjb[sub*16 + quad*4];
      int jbase = jb + sub*16 + quad*4;
      #pragma unroll
      for (int reg = 0; reg < 4; ++reg){
        int gj = jbase + reg;
        float sj = (&sj4.x)[reg];
        #pragma unroll
        for (int s = 0; s < NSETS; ++s){
          float v64 = fmaf(-128.f, acc[s][reg], sj);   // (sj - 2*dot)*64 + VBIAS > 0 always
          unsigned kv = (unsigned)v64;                 // v_cvt_u32_f32
          unsigned key = (kv << 14) + (unsigned)gj;    // v_lshl_add_u32
          ins4(bk[s], key);
        }
      }
    }
    __syncthreads();   // implicit vmcnt(0): drains the prefetch issued ABOVE (old)
  }

  unsigned* Mk = (unsigned*)Xj;            // ITILE x 17 u32 = 17408 B (<= 32768)
  #pragma unroll
  for (int s = 0; s < NSETS; ++s){
    int base = (s*64 + wave*16 + lcol)*MSTRIDE + quad*4;
    #pragma unroll
    for (int e = 0; e < 4; ++e) Mk[base+e] = bk[s][e];
  }
  __syncthreads();
  if (tid < ITILE){
    unsigned fk[4];
    #pragma unroll
    for (int e = 0; e < 4; ++e) fk[e] = KEYMAX;
    #pragma unroll
    for (int s = 0; s < 16; ++s) ins4(fk, Mk[tid*MSTRIDE + s]);
    int g = i0 + tid;
    #pragma unroll
    for (int e = 0; e < 4; ++e)
      candk[(size_t)g*(NSLICE*4) + sl*4 + e] = fk[e];
  }
}

// Rescore (R6-verified, fence-free): mask the self key, rank the 64 packed
// scan keys, take top-8, stage those rows TRANSPOSED in LDS, run the exact
// np-replicating fp32 pipeline: dot = sequential-in-k fp32 FMA chain,
// d2 = fl32(fl32(sq_i+sq_j) - 2*dot). Final rank by (d2, index) lex.
// One wave per node.
__global__ __launch_bounds__(64) void rescore_kernel(const float* __restrict__ x,
                                                     const float* __restrict__ sqf,
                                                     const unsigned* __restrict__ candk,
                                                     int* __restrict__ idx_out,
                                                     int* __restrict__ Bdeg){
  #pragma clang fp contract(off)
  __shared__ float Xi[256];
  __shared__ float Xct[256][NRS+1];   // transposed candidate rows, 9.2 KB
  __shared__ float dex[NRS];
  __shared__ int   sel[NRS];
  int i = blockIdx.x;
  int t = threadIdx.x;            // 0..63
  ((float4*)Xi)[t] = ((const float4*)(x + (size_t)i * HID))[t];
  unsigned kv = candk[(size_t)i*(NSLICE*4) + t];
  if ((kv & 16383u) == (unsigned)i) kv = KEYMAX;   // drop self
  int rank = 0;
  for (int s = 0; s < 64; ++s){
    unsigned ks = __shfl(kv, s);
    rank += (ks < kv) ? 1 : 0;
  }
  if (rank < NRS) sel[rank] = (int)(kv & 16383u);
  __syncthreads();
  {
    int r = t >> 3, seg = t & 7;     // 8 rows x 8 segments
    const float4* src = (const float4*)(x + (size_t)sel[r] * HID);
    #pragma unroll
    for (int m = 0; m < 8; ++m){
      float4 v = src[seg + 8*m];
      int k = 4*(seg + 8*m);
      Xct[k+0][r] = v.x; Xct[k+1][r] = v.y; Xct[k+2][r] = v.z; Xct[k+3][r] = v.w;
    }
  }
  __syncthreads();
  if (t < NRS){
    int j = sel[t];
    float acc = 0.f;
    for (int k = 0; k < 256; ++k) acc = fmaf(Xi[k], Xct[k][t], acc);
    float t1   = sqf[i] + sqf[j];
    float twod = 2.0f * acc;
    dex[t] = t1 - twod;
  }
  __syncthreads();
  if (t == 0){
    unsigned taken = 0;
    #pragma unroll
    for (int k = 0; k < 4; ++k){
      float bdv = FLTMAX; int bj = 0x7fffffff, bs = -1;
      for (int s = 0; s < NRS; ++s){
        if (taken & (1u << s)) continue;
        float d = dex[s]; int j = sel[s];
        if (d < bdv || (d == bdv && j < bj)){ bdv = d; bj = j; bs = s; }
      }
      taken |= 1u << bs;
      idx_out[i*4 + k] = bj;
      atomicAdd(&Bdeg[bj], 1);
    }
  }
}

// out[i][o] = sum_k A[i][k] * W[o][k]   (A: Mx256 f16, W staged f16, out f16)
__global__ __launch_bounds__(256) void gemm_xw(const _Float16* __restrict__ A,
                                               const _Float16* __restrict__ W,
                                               _Float16* __restrict__ out){
  __shared__ unsigned short Ws[64 * LDSK];
  int tid = threadIdx.x;
  int i0 = (blockIdx.x >> 2) * 64;
  int o0 = (blockIdx.x & 3)  * 64;
  int wave = tid >> 6, lane = tid & 63, quad = lane >> 4, lcol = lane & 15;
  load_tile64(Ws, (const unsigned short*)(W + (size_t)o0 * HID), tid);
  f16x8 a[8];
  const _Float16* arow = A + (size_t)(i0 + wave*16 + lcol) * HID + quad*8;
  #pragma unroll
  for (int ks = 0; ks < 8; ++ks) a[ks] = *(const f16x8*)(arow + ks*32);
  __syncthreads();
  #pragma unroll
  for (int sub = 0; sub < 4; ++sub){
    f32x4 acc = {0.f, 0.f, 0.f, 0.f};
    #pragma unroll
    for (int ks = 0; ks < 8; ++ks){
      f16x8 b = *(const f16x8*)&Ws[(sub*16 + lcol)*LDSK + quad*8 + ks*32];
      acc = __builtin_amdgcn_mfma_f32_16x16x32_f16(a[ks], b, acc, 0, 0, 0);
    }
    #pragma unroll
    for (int reg = 0; reg < 4; ++reg)
      out[(size_t)(i0 + wave*16 + quad*4 + reg)*HID + o0 + sub*16 + lcol] = (_Float16)acc[reg];
  }
}

__global__ __launch_bounds__(256) void prefix_kernel(const int* __restrict__ Bdeg,
                                                     int* __restrict__ off,
                                                     int* __restrict__ cursor){
  __shared__ int psum[256];
  __shared__ int excl[256];
  int t = threadIdx.x;
  int base = t * 64;
  int s = 0;
  for (int k = 0; k < 64; ++k) s += Bdeg[base + k];
  psum[t] = s;
  __syncthreads();
  if (t == 0){ int a = 0; for (int k = 0; k < 256; ++k){ excl[k] = a; a += psum[k]; } }
  __syncthreads();
  int a = excl[t];
  for (int k = 0; k < 64; ++k){ int dv = Bdeg[base + k]; off[base+k] = a; cursor[base+k] = a; a += dv; }
}

__global__ __launch_bounds__(256) void fill_kernel(const int* __restrict__ idx,
                                                   int* __restrict__ cursor,
                                                   int* __restrict__ rev){
  int i = blockIdx.x * 256 + threadIdx.x;
  #pragma unroll
  for (int t = 0; t < 4; ++t){
    int e = idx[i*4 + t];
    int p = atomicAdd(&cursor[e], 1);
    rev[p] = i;
  }
}

// E[e] = mean over contributing nodes of xt[node]  (gather via reverse CSR)
// R11: WAVE-PER-EDGE, lane owns 4 channels (f16x4, 8B/lane -> one wave instr
// covers a full 512B row). 8192 concurrent edge-chains (was 2048), unroll-4
// hoists 4 independent rev->row load chains. Accumulation per channel stays
// strictly sequential in k (bit-identical to the R9-verified sum order);
// division s/(float)d kept verbatim.
__global__ __launch_bounds__(256) void efeat_kernel(const _Float16* __restrict__ xt,
                                                    const int* __restrict__ off,
                                                    const int* __restrict__ deg,
                                                    const int* __restrict__ rev,
                                                    _Float16* __restrict__ E){
  int wv   = blockIdx.x * 4 + (threadIdx.x >> 6);   // global wave id
  int lane = threadIdx.x & 63;
  for (int e = wv; e < NN; e += NWV){
    int o = off[e], d = deg[e];
    float s0 = 0.f, s1 = 0.f, s2 = 0.f, s3 = 0.f;
    #pragma unroll 4
    for (int k = 0; k < d; ++k){
      int node = rev[o + k];
      f16x4 v = *(const f16x4*)(xt + (size_t)node * HID + lane * 4);
      s0 += (float)v.x; s1 += (float)v.y; s2 += (float)v.z; s3 += (float)v.w;
    }
    f16x4 w;
    if (d > 0){
      float fd = (float)d;
      w.x = (_Float16)(s0 / fd); w.y = (_Float16)(s1 / fd);
      w.z = (_Float16)(s2 / fd); w.w = (_Float16)(s3 / fd);
    } else {
      w.x = (_Float16)0.f; w.y = (_Float16)0.f; w.z = (_Float16)0.f; w.w = (_Float16)0.f;
    }
    *(f16x4*)(E + (size_t)e * HID + lane * 4) = w;
  }
}

// R11: wave-per-node, lane owns 4 channels; the 4 E-row loads are
// index-independent -> full ILP. Add order matches the R9-verified kernel.
__global__ __launch_bounds__(256) void fin1_kernel(const _Float16* __restrict__ E,
                                                   const int* __restrict__ idx,
                                                   const float* __restrict__ b1,
                                                   const float* __restrict__ pa,
                                                   _Float16* __restrict__ h1){
  int wv   = blockIdx.x * 4 + (threadIdx.x >> 6);
  int lane = threadIdx.x & 63;
  float4 bc = ((const float4*)b1)[lane];
  float a   = pa[0];
  for (int i = wv; i < NN; i += NWV){
    const int* ip = idx + i*4;
    int e0 = ip[0], e1 = ip[1], e2 = ip[2], e3 = ip[3];
    f16x4 v0 = *(const f16x4*)(E + (size_t)e0*HID + lane*4);
    f16x4 v1 = *(const f16x4*)(E + (size_t)e1*HID + lane*4);
    f16x4 v2 = *(const f16x4*)(E + (size_t)e2*HID + lane*4);
    f16x4 v3 = *(const f16x4*)(E + (size_t)e3*HID + lane*4);
    f16x4 w;
    #pragma unroll
    for (int c = 0; c < 4; ++c){
      float s = ((float)v0[c] + (float)v1[c] + (float)v2[c] + (float)v3[c]);
      float acc = 0.25f * s + (&bc.x)[c];
      acc = (acc >= 0.f) ? acc : a * acc;
      w[c] = (_Float16)acc;
    }
    *(f16x4*)(h1 + (size_t)i*HID + lane*4) = w;
  }
}

__global__ __launch_bounds__(256) void fin2_kernel(const _Float16* __restrict__ E,
                                                   const int* __restrict__ idx,
                                                   const float* __restrict__ b2,
                                                   const float* __restrict__ x,
                                                   const float* __restrict__ pa,
                                                   float* __restrict__ out){
  int wv   = blockIdx.x * 4 + (threadIdx.x >> 6);
  int lane = threadIdx.x & 63;
  float4 bc = ((const float4*)b2)[lane];
  float a   = pa[0];
  for (int i = wv; i < NN; i += NWV){
    const int* ip = idx + i*4;
    int e0 = ip[0], e1 = ip[1], e2 = ip[2], e3 = ip[3];
    f16x4 v0 = *(const f16x4*)(E + (size_t)e0*HID + lane*4);
    f16x4 v1 = *(const f16x4*)(E + (size_t)e1*HID + lane*4);
    f16x4 v2 = *(const f16x4*)(E + (size_t)e2*HID + lane*4);
    f16x4 v3 = *(const f16x4*)(E + (size_t)e3*HID + lane*4);
    float4 xr = *(const float4*)(x + (size_t)i*HID + lane*4);
    float4 w;
    #pragma unroll
    for (int c = 0; c < 4; ++c){
      float s = ((float)v0[c] + (float)v1[c] + (float)v2[c] + (float)v3[c]);
      float acc = 0.25f * s + (&bc.x)[c] + (&xr.x)[c];
      acc = (acc >= 0.f) ? acc : a * acc;
      (&w.x)[c] = acc;
    }
    *(float4*)(out + (size_t)i*HID + lane*4) = w;
  }
}

extern "C" void kernel_launch(void* const* d_in, const int* in_sizes, int n_in,
                              void* d_out, int out_size, void* d_ws, size_t ws_size,
                              hipStream_t stream){
  (void)in_sizes; (void)n_in; (void)out_size; (void)ws_size;
  const float* x  = (const float*)d_in[0];
  // d_in[1] = edge_index (int32), unused by the math
  const float* W1 = (const float*)d_in[2];
  const float* b1 = (const float*)d_in[3];
  const float* W2 = (const float*)d_in[4];
  const float* b2 = (const float*)d_in[5];
  const float* pa = (const float*)d_in[6];
  float* out = (float*)d_out;

  char* ws = (char*)d_ws;
  float*  sqf    = (float*) (ws + 0);                        //  64 KB
  int*    idx    = (int*)   (ws + 65536);                    // 256 KB
  int*    Bdeg   = (int*)   (ws + 327680);                   //  64 KB
  int*    offE   = (int*)   (ws + 393216);                   //  64 KB
  int*    cursor = (int*)   (ws + 458752);                   //  64 KB
  int*    rev    = (int*)   (ws + 524288);                   // 256 KB
  _Float16* xh   = (_Float16*)(ws + (size_t)(5<<20));        //   8 MB
  _Float16* W1h  = (_Float16*)(ws + (size_t)(13<<20));       // 128 KB
  _Float16* W2h  = (_Float16*)(ws + (size_t)(13<<20) + 131072);
  _Float16* xt   = (_Float16*)(ws + (size_t)(13<<20) + 262144);            // 8 MB
  _Float16* E    = (_Float16*)(ws + (size_t)(21<<20) + 262144);            // 8 MB
  _Float16* h1   = (_Float16*)(ws + (size_t)(29<<20) + 262144);            // 8 MB
  // candk (NN*64*4B = 4 MB) aliases the xt region: dead until the first
  // gemm_xw (which runs after rescore consumed it) -> no ws growth.
  unsigned* candk = (unsigned*)xt;                           // 4 MB

  prep_kernel   <<<CVTB + NN/16, 256, 0, stream>>>(x, W1, W2, xh, W1h, W2h, sqf, Bdeg);
  knn_kernel    <<<(NN/ITILE/2)*NSLICE, 256, 0, stream>>>(xh, sqf, candk, 0);
  knn_kernel    <<<(NN/ITILE/2)*NSLICE, 256, 0, stream>>>(xh, sqf, candk, NN/2);
  rescore_kernel<<<NN, 64, 0, stream>>>(x, sqf, candk, idx, Bdeg);
  prefix_kernel <<<1, 256, 0, stream>>>(Bdeg, offE, cursor);
  fill_kernel   <<<NN/256, 256, 0, stream>>>(idx, cursor, rev);

  gemm_xw       <<<(NN/64)*4, 256, 0, stream>>>(xh, W1h, xt);
  efeat_kernel  <<<GSB, 256, 0, stream>>>(xt, offE, Bdeg, rev, E);
  fin1_kernel   <<<GSB, 256, 0, stream>>>(E, idx, b1, pa, h1);

  gemm_xw       <<<(NN/64)*4, 256, 0, stream>>>(h1, W2h, xt);
  efeat_kernel  <<<GSB, 256, 0, stream>>>(xt, offE, Bdeg, rev, E);
  fin2_kernel   <<<GSB, 256, 0, stream>>>(E, idx, b2, x, pa, out);
}

// Round 12
// 437.009 us; speedup vs baseline: 2.0557x; 1.0330x over previous
//
#include <hip/hip_runtime.h>
#include <stdint.h>

#define NN   16384
#define HID  256
#define LDSK 264            // padded LDS row stride in f16 elems (gemm body)
#define NSLICE 16           // j sliced 16-way
#define JSL  (NN/NSLICE)    // 1024 j's per slice
#define JT   32             // j-tile rows, 16KB tiles, double-buffered (R5-proven)
#define NIT  (JSL/JT)       // 32 iterations per block
#define NSETS 4             // R6-proven: LDS bytes/eval halved, no spill at (256,2)
#define ITILE (NSETS*64)    // 256 i's per block
#define NRS  8              // exact-rescore chains (top-8 of 64 by scan key)
#define GSB  2048           // grid-stride block count for efeat/fin
#define NWV  (GSB*4)        // 8192 concurrent waves for wave-per-item kernels
#define FLTMAX 3.402823466e38f
#define KEYMAX 0xFFFFFFFFu
#define VBIAS 131072.0f     // folded into sqj64; keeps v64+B > 0 for ALL pairs incl. self
#define MSTRIDE 17          // padded merge stride (u32): tid*17 reads are conflict-free

typedef __attribute__((ext_vector_type(8))) _Float16 f16x8;
typedef __attribute__((ext_vector_type(4))) _Float16 f16x4;
typedef __attribute__((ext_vector_type(4))) float f32x4;

typedef const __attribute__((address_space(1))) unsigned int* gAS1;
typedef __attribute__((address_space(3))) unsigned int* lAS3;

// ---- fused fp32->fp16 convert (x, W1, W2) + np-replicating row sum-of-squares
// ---- + Bdeg zeroing (replaces hipMemsetAsync) ----
// R8 lesson (journal): device-scope __threadfence in a 16k-block kernel costs
// ~240us on gfx950 — NO fence-based fusion; kernel boundaries are the cheap
// cross-block ordering primitive here.
#define NXG (NN*HID/4)
#define NWG (HID*HID/4)
#define CVTB ((NXG + 2*NWG)/256)     // 4224 cvt blocks
__global__ __launch_bounds__(256) void prep_kernel(const float* __restrict__ x,
                                                   const float* __restrict__ W1,
                                                   const float* __restrict__ W2,
                                                   _Float16* __restrict__ xh,
                                                   _Float16* __restrict__ W1h,
                                                   _Float16* __restrict__ W2h,
                                                   float* __restrict__ sqf,
                                                   int* __restrict__ Bdeg){
  #pragma clang fp contract(off)
  int b = blockIdx.x;
  int g0 = b * 256 + threadIdx.x;
  if (g0 < NN) Bdeg[g0] = 0;
  if (b < CVTB){
    int g = g0;
    const float* src; _Float16* dst; int o;
    if (g < NXG)            { src = x;  dst = xh;  o = g; }
    else if (g < NXG + NWG) { src = W1; dst = W1h; o = g - NXG; }
    else                    { src = W2; dst = W2h; o = g - NXG - NWG; }
    float4 v = ((const float4*)src)[o];
    f16x4 h; h.x = (_Float16)v.x; h.y = (_Float16)v.y; h.z = (_Float16)v.z; h.w = (_Float16)v.w;
    ((f16x4*)dst)[o] = h;
  } else {
    int bb = b - CVTB;
    int lane = threadIdx.x & 63;
    int rw   = lane >> 4;
    int h    = (lane >> 3) & 1;
    int j    = lane & 7;
    int row  = (bb * 4 + (threadIdx.x >> 6)) * 4 + rw;
    const float* p = x + (size_t)row * HID + h*128 + j;
    float v0 = p[0];
    float r  = v0 * v0;
    #pragma unroll
    for (int i = 1; i < 16; ++i){ float v = p[i*8]; float m = v * v; r = r + m; }
    float t1 = r  + __shfl_xor(r,  1);
    float t2 = t1 + __shfl_xor(t1, 2);
    float t3 = t2 + __shfl_xor(t2, 4);
    float tot = t3 + __shfl_xor(t3, 8);
    if (h == 0 && j == 0) sqf[row] = tot;
  }
}

// stage 64x256 f16 tile into LDS with padded stride (256 threads) — gemm body
__device__ __forceinline__ void load_tile64(unsigned short* dst, const unsigned short* src, int tid){
  const uint4* s = (const uint4*)src;
  #pragma unroll
  for (int r = 0; r < 8; ++r){
    int fl  = tid + (r << 8);
    int row = fl >> 5;
    int c   = fl & 31;
    *(uint4*)&dst[row*LDSK + (c << 3)] = s[fl];
  }
}

// 4-op sorted-ascending top-4 insert (R6-proven):
// b0'=min(k,b0); bN'=med3(k,b(N-1),bN)
__device__ __forceinline__ unsigned umed3(unsigned a, unsigned b, unsigned c){
  unsigned d;
  asm("v_med3_u32 %0, %1, %2, %3" : "=v"(d) : "v"(a), "v"(b), "v"(c));
  return d;
}
__device__ __forceinline__ void ins4(unsigned (&b)[4], unsigned k){
  unsigned b0 = b[0], b1 = b[1], b2 = b[2];
  b[0] = k < b0 ? k : b0;          // v_min_u32
  b[1] = umed3(k, b0, b1);
  b[2] = umed3(k, b1, b2);
  b[3] = umed3(k, b2, b[3]);
}

// fp16 MFMA Gram, swapped operands, FOUR stationary i-sets/wave (R6-proven).
// XOR-swizzled row-major LDS (R5-proven). R12: COUNTED-VMCNT PIPELINE —
// R11's audit showed knn at ~4x its SIMD issue floor: the per-iter
// __syncthreads() drained vmcnt(0), exposing full prefetch latency at only
// 2 blocks/CU. New loop (catalog T3/T4-minimal):
//   issue prefetch(it+1) -> s_waitcnt vmcnt(4) (current tile's 4 older loads
//   landed; next tile's 4 stay IN FLIGHT) -> raw s_barrier (A) -> compute ->
//   lgkmcnt(0) -> raw s_barrier (B).
// Race audit: prefetch(it+1) overwrites buf[(it+1)&1], last read at it-1,
// protected by barrier-B(it-1); compute(it) protected by vmcnt+barrier-A.
// sched_barrier(0) after each barrier pins hoisting (guide rule #18).
// Prereq: sqj64 for the WHOLE slice pre-staged in prologue (4KB LDS) — a
// per-iter sqf load would make the compiler wait on the youngest vmem op
// (= vmcnt(0)), re-introducing the drain.
__global__ __launch_bounds__(256, 2) void knn_kernel(const _Float16* __restrict__ xh,
                                                     const float* __restrict__ sqf,
                                                     unsigned* __restrict__ candk){
  __shared__ __align__(16) unsigned short Xj[2][JT*256];  // 2 x 16KB swizzled tiles; aliased as merge buf
  __shared__ __align__(16) float sqjA[JSL];               // 4KB: whole slice, sq_j*64 + VBIAS

  int tid  = threadIdx.x;
  int sl   = blockIdx.x & (NSLICE-1);
  int i0   = (blockIdx.x / NSLICE) * ITILE;
  int jb0  = sl * JSL;
  int wave = tid >> 6, lane = tid & 63, quad = lane >> 4, lcol = lane & 15;

  f16x8 bfr[NSETS][8];
  #pragma unroll
  for (int s = 0; s < NSETS; ++s){
    const _Float16* br = xh + (size_t)(i0 + s*64 + wave*16 + lcol) * HID + quad*8;
    #pragma unroll
    for (int ks = 0; ks < 8; ++ks) bfr[s][ks] = *(const f16x8*)(br + ks*32);
  }

  const _Float16* gsrc[4];
  #pragma unroll
  for (int r = 0; r < 4; ++r){
    int m   = r*256 + tid;
    int row = m >> 5;
    int ch  = m & 31;
    gsrc[r] = xh + (size_t)row * HID + ((ch ^ (row & 7)) << 3);
  }

  int b0 = lcol*512 + ((quad ^ (lcol & 3)) << 4) + (((lcol >> 2) & 1) << 6);
  int b1 = b0 ^ 64;

  unsigned bk[NSETS][4];
  #pragma unroll
  for (int s = 0; s < NSETS; ++s)
    #pragma unroll
    for (int e = 0; e < 4; ++e) bk[s][e] = KEYMAX;

  // prologue: whole-slice sqj (4 floats/thread) + tile 0; one-time full drain
  {
    float4 sv = ((const float4*)(sqf + jb0))[tid];
    float4 sw;
    sw.x = fmaf(sv.x, 64.f, VBIAS); sw.y = fmaf(sv.y, 64.f, VBIAS);
    sw.z = fmaf(sv.z, 64.f, VBIAS); sw.w = fmaf(sv.w, 64.f, VBIAS);
    ((float4*)sqjA)[tid] = sw;
    size_t joff = (size_t)jb0 * HID;
    #pragma unroll
    for (int r = 0; r < 4; ++r)
      __builtin_amdgcn_global_load_lds((gAS1)(const void*)(gsrc[r] + joff),
                                       (lAS3)(void*)&Xj[0][(r*256 + tid) * 8],
                                       16, 0, 0);
    asm volatile("s_waitcnt vmcnt(0) lgkmcnt(0)" ::: "memory");
  }
  __builtin_amdgcn_s_barrier();
  __builtin_amdgcn_sched_barrier(0);

  for (int it = 0; it < NIT; ++it){
    int cur = it & 1;
    if (it + 1 < NIT){
      int nb = cur ^ 1;
      int jn = jb0 + (it + 1) * JT;
      size_t joff = (size_t)jn * HID;
      #pragma unroll
      for (int r = 0; r < 4; ++r)
        __builtin_amdgcn_global_load_lds((gAS1)(const void*)(gsrc[r] + joff),
                                         (lAS3)(void*)&Xj[nb][(r*256 + tid) * 8],
                                         16, 0, 0);
      asm volatile("s_waitcnt vmcnt(4)" ::: "memory");   // tile it landed; tile it+1 in flight
    } else {
      asm volatile("s_waitcnt vmcnt(0)" ::: "memory");   // final tile: nothing younger
    }
    __builtin_amdgcn_s_barrier();                        // barrier-A
    __builtin_amdgcn_sched_barrier(0);

    const char*  tb  = (const char*)&Xj[cur][0];
    const float* sjb = &sqjA[it * JT];
    int jb = jb0 + it * JT;

    #pragma unroll
    for (int sub = 0; sub < 2; ++sub){
      f32x4 acc[NSETS];
      #pragma unroll
      for (int s = 0; s < NSETS; ++s) acc[s] = (f32x4){0.f,0.f,0.f,0.f};
      #pragma unroll
      for (int ks = 0; ks < 8; ++ks){
        f16x8 a = *(const f16x8*)(tb + sub*8192 + ((ks >> 1) << 7) + ((ks & 1) ? b1 : b0));
        #pragma unroll
        for (int s = 0; s < NSETS; ++s)
          acc[s] = __builtin_amdgcn_mfma_f32_16x16x32_f16(a, bfr[s][ks], acc[s], 0, 0, 0);
      }
      float4 sj4 = *(const float4*)&sjb[sub*16 + quad*4];
      int jbase = jb + sub*16 + quad*4;
      #pragma unroll
      for (int reg = 0; reg < 4; ++reg){
        int gj = jbase + reg;
        float sj = (&sj4.x)[reg];
        #pragma unroll
        for (int s = 0; s < NSETS; ++s){
          float v64 = fmaf(-128.f, acc[s][reg], sj);   // (sj - 2*dot)*64 + VBIAS > 0 always
          unsigned kv = (unsigned)v64;                 // v_cvt_u32_f32
          unsigned key = (kv << 14) + (unsigned)gj;    // v_lshl_add_u32
          ins4(bk[s], key);
        }
      }
    }
    asm volatile("s_waitcnt lgkmcnt(0)" ::: "memory");
    __builtin_amdgcn_s_barrier();                        // barrier-B: buf[cur] reads done
    __builtin_amdgcn_sched_barrier(0);
  }

  // merge across the 4 quads per i: 16 keys -> top-4 (LDS aliased on Xj, stride 17)
  unsigned* Mk = (unsigned*)Xj;            // ITILE x 17 u32 = 17408 B (<= 32768)
  #pragma unroll
  for (int s = 0; s < NSETS; ++s){
    int base = (s*64 + wave*16 + lcol)*MSTRIDE + quad*4;
    #pragma unroll
    for (int e = 0; e < 4; ++e) Mk[base+e] = bk[s][e];
  }
  __syncthreads();
  if (tid < ITILE){
    unsigned fk[4];
    #pragma unroll
    for (int e = 0; e < 4; ++e) fk[e] = KEYMAX;
    #pragma unroll
    for (int s = 0; s < 16; ++s) ins4(fk, Mk[tid*MSTRIDE + s]);
    int g = i0 + tid;
    #pragma unroll
    for (int e = 0; e < 4; ++e)
      candk[(size_t)g*(NSLICE*4) + sl*4 + e] = fk[e];
  }
}

// Rescore (R6-verified, fence-free): mask the self key, rank the 64 packed
// scan keys, take top-8, stage those rows TRANSPOSED in LDS, run the exact
// np-replicating fp32 pipeline: dot = sequential-in-k fp32 FMA chain,
// d2 = fl32(fl32(sq_i+sq_j) - 2*dot). Final rank by (d2, index) lex.
// One wave per node.
__global__ __launch_bounds__(64) void rescore_kernel(const float* __restrict__ x,
                                                     const float* __restrict__ sqf,
                                                     const unsigned* __restrict__ candk,
                                                     int* __restrict__ idx_out,
                                                     int* __restrict__ Bdeg){
  #pragma clang fp contract(off)
  __shared__ float Xi[256];
  __shared__ float Xct[256][NRS+1];   // transposed candidate rows, 9.2 KB
  __shared__ float dex[NRS];
  __shared__ int   sel[NRS];
  int i = blockIdx.x;
  int t = threadIdx.x;            // 0..63
  ((float4*)Xi)[t] = ((const float4*)(x + (size_t)i * HID))[t];
  unsigned kv = candk[(size_t)i*(NSLICE*4) + t];
  if ((kv & 16383u) == (unsigned)i) kv = KEYMAX;   // drop self
  int rank = 0;
  for (int s = 0; s < 64; ++s){
    unsigned ks = __shfl(kv, s);
    rank += (ks < kv) ? 1 : 0;
  }
  if (rank < NRS) sel[rank] = (int)(kv & 16383u);
  __syncthreads();
  {
    int r = t >> 3, seg = t & 7;     // 8 rows x 8 segments
    const float4* src = (const float4*)(x + (size_t)sel[r] * HID);
    #pragma unroll
    for (int m = 0; m < 8; ++m){
      float4 v = src[seg + 8*m];
      int k = 4*(seg + 8*m);
      Xct[k+0][r] = v.x; Xct[k+1][r] = v.y; Xct[k+2][r] = v.z; Xct[k+3][r] = v.w;
    }
  }
  __syncthreads();
  if (t < NRS){
    int j = sel[t];
    float acc = 0.f;
    for (int k = 0; k < 256; ++k) acc = fmaf(Xi[k], Xct[k][t], acc);
    float t1   = sqf[i] + sqf[j];
    float twod = 2.0f * acc;
    dex[t] = t1 - twod;
  }
  __syncthreads();
  if (t == 0){
    unsigned taken = 0;
    #pragma unroll
    for (int k = 0; k < 4; ++k){
      float bdv = FLTMAX; int bj = 0x7fffffff, bs = -1;
      for (int s = 0; s < NRS; ++s){
        if (taken & (1u << s)) continue;
        float d = dex[s]; int j = sel[s];
        if (d < bdv || (d == bdv && j < bj)){ bdv = d; bj = j; bs = s; }
      }
      taken |= 1u << bs;
      idx_out[i*4 + k] = bj;
      atomicAdd(&Bdeg[bj], 1);
    }
  }
}

// out[i][o] = sum_k A[i][k] * W[o][k]   (A: Mx256 f16, W staged f16, out f16)
__global__ __launch_bounds__(256) void gemm_xw(const _Float16* __restrict__ A,
                                               const _Float16* __restrict__ W,
                                               _Float16* __restrict__ out){
  __shared__ unsigned short Ws[64 * LDSK];
  int tid = threadIdx.x;
  int i0 = (blockIdx.x >> 2) * 64;
  int o0 = (blockIdx.x & 3)  * 64;
  int wave = tid >> 6, lane = tid & 63, quad = lane >> 4, lcol = lane & 15;
  load_tile64(Ws, (const unsigned short*)(W + (size_t)o0 * HID), tid);
  f16x8 a[8];
  const _Float16* arow = A + (size_t)(i0 + wave*16 + lcol) * HID + quad*8;
  #pragma unroll
  for (int ks = 0; ks < 8; ++ks) a[ks] = *(const f16x8*)(arow + ks*32);
  __syncthreads();
  #pragma unroll
  for (int sub = 0; sub < 4; ++sub){
    f32x4 acc = {0.f, 0.f, 0.f, 0.f};
    #pragma unroll
    for (int ks = 0; ks < 8; ++ks){
      f16x8 b = *(const f16x8*)&Ws[(sub*16 + lcol)*LDSK + quad*8 + ks*32];
      acc = __builtin_amdgcn_mfma_f32_16x16x32_f16(a[ks], b, acc, 0, 0, 0);
    }
    #pragma unroll
    for (int reg = 0; reg < 4; ++reg)
      out[(size_t)(i0 + wave*16 + quad*4 + reg)*HID + o0 + sub*16 + lcol] = (_Float16)acc[reg];
  }
}

__global__ __launch_bounds__(256) void prefix_kernel(const int* __restrict__ Bdeg,
                                                     int* __restrict__ off,
                                                     int* __restrict__ cursor){
  __shared__ int psum[256];
  __shared__ int excl[256];
  int t = threadIdx.x;
  int base = t * 64;
  int s = 0;
  for (int k = 0; k < 64; ++k) s += Bdeg[base + k];
  psum[t] = s;
  __syncthreads();
  if (t == 0){ int a = 0; for (int k = 0; k < 256; ++k){ excl[k] = a; a += psum[k]; } }
  __syncthreads();
  int a = excl[t];
  for (int k = 0; k < 64; ++k){ int dv = Bdeg[base + k]; off[base+k] = a; cursor[base+k] = a; a += dv; }
}

__global__ __launch_bounds__(256) void fill_kernel(const int* __restrict__ idx,
                                                   int* __restrict__ cursor,
                                                   int* __restrict__ rev){
  int i = blockIdx.x * 256 + threadIdx.x;
  #pragma unroll
  for (int t = 0; t < 4; ++t){
    int e = idx[i*4 + t];
    int p = atomicAdd(&cursor[e], 1);
    rev[p] = i;
  }
}

// E[e] = mean over contributing nodes of xt[node]  (gather via reverse CSR)
// R11-proven: wave-per-edge, lane owns 4 channels (f16x4), unroll-4 ILP.
__global__ __launch_bounds__(256) void efeat_kernel(const _Float16* __restrict__ xt,
                                                    const int* __restrict__ off,
                                                    const int* __restrict__ deg,
                                                    const int* __restrict__ rev,
                                                    _Float16* __restrict__ E){
  int wv   = blockIdx.x * 4 + (threadIdx.x >> 6);   // global wave id
  int lane = threadIdx.x & 63;
  for (int e = wv; e < NN; e += NWV){
    int o = off[e], d = deg[e];
    float s0 = 0.f, s1 = 0.f, s2 = 0.f, s3 = 0.f;
    #pragma unroll 4
    for (int k = 0; k < d; ++k){
      int node = rev[o + k];
      f16x4 v = *(const f16x4*)(xt + (size_t)node * HID + lane * 4);
      s0 += (float)v.x; s1 += (float)v.y; s2 += (float)v.z; s3 += (float)v.w;
    }
    f16x4 w;
    if (d > 0){
      float fd = (float)d;
      w.x = (_Float16)(s0 / fd); w.y = (_Float16)(s1 / fd);
      w.z = (_Float16)(s2 / fd); w.w = (_Float16)(s3 / fd);
    } else {
      w.x = (_Float16)0.f; w.y = (_Float16)0.f; w.z = (_Float16)0.f; w.w = (_Float16)0.f;
    }
    *(f16x4*)(E + (size_t)e * HID + lane * 4) = w;
  }
}

// R11-proven: wave-per-node, lane owns 4 channels; 4 independent E-row loads.
__global__ __launch_bounds__(256) void fin1_kernel(const _Float16* __restrict__ E,
                                                   const int* __restrict__ idx,
                                                   const float* __restrict__ b1,
                                                   const float* __restrict__ pa,
                                                   _Float16* __restrict__ h1){
  int wv   = blockIdx.x * 4 + (threadIdx.x >> 6);
  int lane = threadIdx.x & 63;
  float4 bc = ((const float4*)b1)[lane];
  float a   = pa[0];
  for (int i = wv; i < NN; i += NWV){
    const int* ip = idx + i*4;
    int e0 = ip[0], e1 = ip[1], e2 = ip[2], e3 = ip[3];
    f16x4 v0 = *(const f16x4*)(E + (size_t)e0*HID + lane*4);
    f16x4 v1 = *(const f16x4*)(E + (size_t)e1*HID + lane*4);
    f16x4 v2 = *(const f16x4*)(E + (size_t)e2*HID + lane*4);
    f16x4 v3 = *(const f16x4*)(E + (size_t)e3*HID + lane*4);
    f16x4 w;
    #pragma unroll
    for (int c = 0; c < 4; ++c){
      float s = ((float)v0[c] + (float)v1[c] + (float)v2[c] + (float)v3[c]);
      float acc = 0.25f * s + (&bc.x)[c];
      acc = (acc >= 0.f) ? acc : a * acc;
      w[c] = (_Float16)acc;
    }
    *(f16x4*)(h1 + (size_t)i*HID + lane*4) = w;
  }
}

__global__ __launch_bounds__(256) void fin2_kernel(const _Float16* __restrict__ E,
                                                   const int* __restrict__ idx,
                                                   const float* __restrict__ b2,
                                                   const float* __restrict__ x,
                                                   const float* __restrict__ pa,
                                                   float* __restrict__ out){
  int wv   = blockIdx.x * 4 + (threadIdx.x >> 6);
  int lane = threadIdx.x & 63;
  float4 bc = ((const float4*)b2)[lane];
  float a   = pa[0];
  for (int i = wv; i < NN; i += NWV){
    const int* ip = idx + i*4;
    int e0 = ip[0], e1 = ip[1], e2 = ip[2], e3 = ip[3];
    f16x4 v0 = *(const f16x4*)(E + (size_t)e0*HID + lane*4);
    f16x4 v1 = *(const f16x4*)(E + (size_t)e1*HID + lane*4);
    f16x4 v2 = *(const f16x4*)(E + (size_t)e2*HID + lane*4);
    f16x4 v3 = *(const f16x4*)(E + (size_t)e3*HID + lane*4);
    float4 xr = *(const float4*)(x + (size_t)i*HID + lane*4);
    float4 w;
    #pragma unroll
    for (int c = 0; c < 4; ++c){
      float s = ((float)v0[c] + (float)v1[c] + (float)v2[c] + (float)v3[c]);
      float acc = 0.25f * s + (&bc.x)[c] + (&xr.x)[c];
      acc = (acc >= 0.f) ? acc : a * acc;
      (&w.x)[c] = acc;
    }
    *(float4*)(out + (size_t)i*HID + lane*4) = w;
  }
}

extern "C" void kernel_launch(void* const* d_in, const int* in_sizes, int n_in,
                              void* d_out, int out_size, void* d_ws, size_t ws_size,
                              hipStream_t stream){
  (void)in_sizes; (void)n_in; (void)out_size; (void)ws_size;
  const float* x  = (const float*)d_in[0];
  // d_in[1] = edge_index (int32), unused by the math
  const float* W1 = (const float*)d_in[2];
  const float* b1 = (const float*)d_in[3];
  const float* W2 = (const float*)d_in[4];
  const float* b2 = (const float*)d_in[5];
  const float* pa = (const float*)d_in[6];
  float* out = (float*)d_out;

  char* ws = (char*)d_ws;
  float*  sqf    = (float*) (ws + 0);                        //  64 KB
  int*    idx    = (int*)   (ws + 65536);                    // 256 KB
  int*    Bdeg   = (int*)   (ws + 327680);                   //  64 KB
  int*    offE   = (int*)   (ws + 393216);                   //  64 KB
  int*    cursor = (int*)   (ws + 458752);                   //  64 KB
  int*    rev    = (int*)   (ws + 524288);                   // 256 KB
  _Float16* xh   = (_Float16*)(ws + (size_t)(5<<20));        //   8 MB
  _Float16* W1h  = (_Float16*)(ws + (size_t)(13<<20));       // 128 KB
  _Float16* W2h  = (_Float16*)(ws + (size_t)(13<<20) + 131072);
  _Float16* xt   = (_Float16*)(ws + (size_t)(13<<20) + 262144);            // 8 MB
  _Float16* E    = (_Float16*)(ws + (size_t)(21<<20) + 262144);            // 8 MB
  _Float16* h1   = (_Float16*)(ws + (size_t)(29<<20) + 262144);            // 8 MB
  // candk (NN*64*4B = 4 MB) aliases the xt region: dead until the first
  // gemm_xw (which runs after rescore consumed it) -> no ws growth.
  unsigned* candk = (unsigned*)xt;                           // 4 MB

  prep_kernel   <<<CVTB + NN/16, 256, 0, stream>>>(x, W1, W2, xh, W1h, W2h, sqf, Bdeg);
  knn_kernel    <<<(NN/ITILE)*NSLICE, 256, 0, stream>>>(xh, sqf, candk);
  rescore_kernel<<<NN, 64, 0, stream>>>(x, sqf, candk, idx, Bdeg);
  prefix_kernel <<<1, 256, 0, stream>>>(Bdeg, offE, cursor);
  fill_kernel   <<<NN/256, 256, 0, stream>>>(idx, cursor, rev);

  gemm_xw       <<<(NN/64)*4, 256, 0, stream>>>(xh, W1h, xt);
  efeat_kernel  <<<GSB, 256, 0, stream>>>(xt, offE, Bdeg, rev, E);
  fin1_kernel   <<<GSB, 256, 0, stream>>>(E, idx, b1, pa, h1);

  gemm_xw       <<<(NN/64)*4, 256, 0, stream>>>(h1, W2h, xt);
  efeat_kernel  <<<GSB, 256, 0, stream>>>(xt, offE, Bdeg, rev, E);
  fin2_kernel   <<<GSB, 256, 0, stream>>>(E, idx, b2, x, pa, out);
}

// Round 13
// 421.915 us; speedup vs baseline: 2.1293x; 1.0358x over previous
//
#include <hip/hip_runtime.h>
#include <stdint.h>

#define NN   16384
#define HID  256
#define LDSK 264            // padded LDS row stride in f16 elems (gemm body)
#define NSLICE 16           // j sliced 16-way
#define JSL  (NN/NSLICE)    // 1024 j's per slice
#define JT   32             // j-tile rows, 16KB tiles, double-buffered (R5-proven)
#define NIT  (JSL/JT)       // 32 iterations per block
#define NSETS 4             // R6-proven: LDS bytes/eval halved, no spill at (256,2)
#define ITILE (NSETS*64)    // 256 i's per block
#define NRS  8              // exact-rescore chains (top-8 of 64 by scan key)
#define GSB  2048           // grid-stride block count for efeat/fin
#define NWV  (GSB*4)        // 8192 concurrent waves for wave-per-item kernels
#define FLTMAX 3.402823466e38f
#define KEYMAX 0xFFFFFFFFu
#define VBIAS 131072.0f     // folded into sqj64; keeps v64+B > 0 for ALL pairs incl. self
#define MSTRIDE 17          // padded merge stride (u32): tid*17 reads are conflict-free

typedef __attribute__((ext_vector_type(8))) _Float16 f16x8;
typedef __attribute__((ext_vector_type(4))) _Float16 f16x4;
typedef __attribute__((ext_vector_type(4))) float f32x4;

typedef const __attribute__((address_space(1))) unsigned int* gAS1;
typedef __attribute__((address_space(3))) unsigned int* lAS3;

// ---- fused fp32->fp16 convert (x, W1, W2) + np-replicating row sum-of-squares
// ---- + Bdeg zeroing (replaces hipMemsetAsync) ----
// R8 lesson (journal): device-scope __threadfence in a 16k-block kernel costs
// ~240us on gfx950 — NO fence-based fusion; kernel boundaries are the cheap
// cross-block ordering primitive here.
#define NXG (NN*HID/4)
#define NWG (HID*HID/4)
#define CVTB ((NXG + 2*NWG)/256)     // 4224 cvt blocks
__global__ __launch_bounds__(256) void prep_kernel(const float* __restrict__ x,
                                                   const float* __restrict__ W1,
                                                   const float* __restrict__ W2,
                                                   _Float16* __restrict__ xh,
                                                   _Float16* __restrict__ W1h,
                                                   _Float16* __restrict__ W2h,
                                                   float* __restrict__ sqf,
                                                   int* __restrict__ Bdeg){
  #pragma clang fp contract(off)
  int b = blockIdx.x;
  int g0 = b * 256 + threadIdx.x;
  if (g0 < NN) Bdeg[g0] = 0;
  if (b < CVTB){
    int g = g0;
    const float* src; _Float16* dst; int o;
    if (g < NXG)            { src = x;  dst = xh;  o = g; }
    else if (g < NXG + NWG) { src = W1; dst = W1h; o = g - NXG; }
    else                    { src = W2; dst = W2h; o = g - NXG - NWG; }
    float4 v = ((const float4*)src)[o];
    f16x4 h; h.x = (_Float16)v.x; h.y = (_Float16)v.y; h.z = (_Float16)v.z; h.w = (_Float16)v.w;
    ((f16x4*)dst)[o] = h;
  } else {
    int bb = b - CVTB;
    int lane = threadIdx.x & 63;
    int rw   = lane >> 4;
    int h    = (lane >> 3) & 1;
    int j    = lane & 7;
    int row  = (bb * 4 + (threadIdx.x >> 6)) * 4 + rw;
    const float* p = x + (size_t)row * HID + h*128 + j;
    float v0 = p[0];
    float r  = v0 * v0;
    #pragma unroll
    for (int i = 1; i < 16; ++i){ float v = p[i*8]; float m = v * v; r = r + m; }
    float t1 = r  + __shfl_xor(r,  1);
    float t2 = t1 + __shfl_xor(t1, 2);
    float t3 = t2 + __shfl_xor(t2, 4);
    float tot = t3 + __shfl_xor(t3, 8);
    if (h == 0 && j == 0) sqf[row] = tot;
  }
}

// stage 64x256 f16 tile into LDS with padded stride (256 threads) — gemm body
__device__ __forceinline__ void load_tile64(unsigned short* dst, const unsigned short* src, int tid){
  const uint4* s = (const uint4*)src;
  #pragma unroll
  for (int r = 0; r < 8; ++r){
    int fl  = tid + (r << 8);
    int row = fl >> 5;
    int c   = fl & 31;
    *(uint4*)&dst[row*LDSK + (c << 3)] = s[fl];
  }
}

// 4-op sorted-ascending top-4 insert (R6-proven):
// b0'=min(k,b0); bN'=med3(k,b(N-1),bN)
__device__ __forceinline__ unsigned umed3(unsigned a, unsigned b, unsigned c){
  unsigned d;
  asm("v_med3_u32 %0, %1, %2, %3" : "=v"(d) : "v"(a), "v"(b), "v"(c));
  return d;
}
__device__ __forceinline__ void ins4(unsigned (&b)[4], unsigned k){
  unsigned b0 = b[0], b1 = b[1], b2 = b[2];
  b[0] = k < b0 ? k : b0;          // v_min_u32
  b[1] = umed3(k, b0, b1);
  b[2] = umed3(k, b1, b2);
  b[3] = umed3(k, b2, b[3]);
}

// fp16 MFMA Gram, swapped operands, FOUR stationary i-sets/wave (R6-proven).
// XOR-swizzled row-major LDS (R5-proven). R12-proven COUNTED-VMCNT PIPELINE:
//   issue prefetch(it+1) -> s_waitcnt vmcnt(4) -> raw s_barrier (A) ->
//   compute -> lgkmcnt(0) -> raw s_barrier (B). sqj for the whole slice
//   pre-staged in the prologue (no per-iter register-consumed vmem).
__global__ __launch_bounds__(256, 2) void knn_kernel(const _Float16* __restrict__ xh,
                                                     const float* __restrict__ sqf,
                                                     unsigned* __restrict__ candk){
  __shared__ __align__(16) unsigned short Xj[2][JT*256];  // 2 x 16KB swizzled tiles; aliased as merge buf
  __shared__ __align__(16) float sqjA[JSL];               // 4KB: whole slice, sq_j*64 + VBIAS

  int tid  = threadIdx.x;
  int sl   = blockIdx.x & (NSLICE-1);
  int i0   = (blockIdx.x / NSLICE) * ITILE;
  int jb0  = sl * JSL;
  int wave = tid >> 6, lane = tid & 63, quad = lane >> 4, lcol = lane & 15;

  f16x8 bfr[NSETS][8];
  #pragma unroll
  for (int s = 0; s < NSETS; ++s){
    const _Float16* br = xh + (size_t)(i0 + s*64 + wave*16 + lcol) * HID + quad*8;
    #pragma unroll
    for (int ks = 0; ks < 8; ++ks) bfr[s][ks] = *(const f16x8*)(br + ks*32);
  }

  const _Float16* gsrc[4];
  #pragma unroll
  for (int r = 0; r < 4; ++r){
    int m   = r*256 + tid;
    int row = m >> 5;
    int ch  = m & 31;
    gsrc[r] = xh + (size_t)row * HID + ((ch ^ (row & 7)) << 3);
  }

  int b0 = lcol*512 + ((quad ^ (lcol & 3)) << 4) + (((lcol >> 2) & 1) << 6);
  int b1 = b0 ^ 64;

  unsigned bk[NSETS][4];
  #pragma unroll
  for (int s = 0; s < NSETS; ++s)
    #pragma unroll
    for (int e = 0; e < 4; ++e) bk[s][e] = KEYMAX;

  // prologue: whole-slice sqj (4 floats/thread) + tile 0; one-time full drain
  {
    float4 sv = ((const float4*)(sqf + jb0))[tid];
    float4 sw;
    sw.x = fmaf(sv.x, 64.f, VBIAS); sw.y = fmaf(sv.y, 64.f, VBIAS);
    sw.z = fmaf(sv.z, 64.f, VBIAS); sw.w = fmaf(sv.w, 64.f, VBIAS);
    ((float4*)sqjA)[tid] = sw;
    size_t joff = (size_t)jb0 * HID;
    #pragma unroll
    for (int r = 0; r < 4; ++r)
      __builtin_amdgcn_global_load_lds((gAS1)(const void*)(gsrc[r] + joff),
                                       (lAS3)(void*)&Xj[0][(r*256 + tid) * 8],
                                       16, 0, 0);
    asm volatile("s_waitcnt vmcnt(0) lgkmcnt(0)" ::: "memory");
  }
  __builtin_amdgcn_s_barrier();
  __builtin_amdgcn_sched_barrier(0);

  for (int it = 0; it < NIT; ++it){
    int cur = it & 1;
    if (it + 1 < NIT){
      int nb = cur ^ 1;
      int jn = jb0 + (it + 1) * JT;
      size_t joff = (size_t)jn * HID;
      #pragma unroll
      for (int r = 0; r < 4; ++r)
        __builtin_amdgcn_global_load_lds((gAS1)(const void*)(gsrc[r] + joff),
                                         (lAS3)(void*)&Xj[nb][(r*256 + tid) * 8],
                                         16, 0, 0);
      asm volatile("s_waitcnt vmcnt(4)" ::: "memory");   // tile it landed; tile it+1 in flight
    } else {
      asm volatile("s_waitcnt vmcnt(0)" ::: "memory");   // final tile: nothing younger
    }
    __builtin_amdgcn_s_barrier();                        // barrier-A
    __builtin_amdgcn_sched_barrier(0);

    const char*  tb  = (const char*)&Xj[cur][0];
    const float* sjb = &sqjA[it * JT];
    int jb = jb0 + it * JT;

    #pragma unroll
    for (int sub = 0; sub < 2; ++sub){
      f32x4 acc[NSETS];
      #pragma unroll
      for (int s = 0; s < NSETS; ++s) acc[s] = (f32x4){0.f,0.f,0.f,0.f};
      #pragma unroll
      for (int ks = 0; ks < 8; ++ks){
        f16x8 a = *(const f16x8*)(tb + sub*8192 + ((ks >> 1) << 7) + ((ks & 1) ? b1 : b0));
        #pragma unroll
        for (int s = 0; s < NSETS; ++s)
          acc[s] = __builtin_amdgcn_mfma_f32_16x16x32_f16(a, bfr[s][ks], acc[s], 0, 0, 0);
      }
      float4 sj4 = *(const float4*)&sjb[sub*16 + quad*4];
      int jbase = jb + sub*16 + quad*4;
      #pragma unroll
      for (int reg = 0; reg < 4; ++reg){
        int gj = jbase + reg;
        float sj = (&sj4.x)[reg];
        #pragma unroll
        for (int s = 0; s < NSETS; ++s){
          float v64 = fmaf(-128.f, acc[s][reg], sj);   // (sj - 2*dot)*64 + VBIAS > 0 always
          unsigned kv = (unsigned)v64;                 // v_cvt_u32_f32
          unsigned key = (kv << 14) + (unsigned)gj;    // v_lshl_add_u32
          ins4(bk[s], key);
        }
      }
    }
    asm volatile("s_waitcnt lgkmcnt(0)" ::: "memory");
    __builtin_amdgcn_s_barrier();                        // barrier-B: buf[cur] reads done
    __builtin_amdgcn_sched_barrier(0);
  }

  // merge across the 4 quads per i: 16 keys -> top-4 (LDS aliased on Xj, stride 17)
  unsigned* Mk = (unsigned*)Xj;            // ITILE x 17 u32 = 17408 B (<= 32768)
  #pragma unroll
  for (int s = 0; s < NSETS; ++s){
    int base = (s*64 + wave*16 + lcol)*MSTRIDE + quad*4;
    #pragma unroll
    for (int e = 0; e < 4; ++e) Mk[base+e] = bk[s][e];
  }
  __syncthreads();
  if (tid < ITILE){
    unsigned fk[4];
    #pragma unroll
    for (int e = 0; e < 4; ++e) fk[e] = KEYMAX;
    #pragma unroll
    for (int s = 0; s < 16; ++s) ins4(fk, Mk[tid*MSTRIDE + s]);
    int g = i0 + tid;
    #pragma unroll
    for (int e = 0; e < 4; ++e)
      candk[(size_t)g*(NSLICE*4) + sl*4 + e] = fk[e];
  }
}

// Rescore R13: 8 nodes per 64-thread block, ONE (node,candidate) chain per
// lane — all 64 lanes run the 256-FMA exact chain simultaneously (old form
// had 8/64 lanes active + an LDS transpose stage; serial-lane anti-pattern,
// ~65us). Chain math BYTE-IDENTICAL: ascending-k fmaf chain on fp32 rows
// (now read directly from global, L3-resident — load path doesn't affect
// numerics), d2 = fl32(fl32(sq_i+sq_j) - 2*acc), final top-4 by (d2, index)
// lex, contract(off). Rank semantics identical: keys distinct, self->KEYMAX,
// rank = #{smaller}; rank<8 selects. Mk padded to 65 -> rank-loop LDS reads
// are 8-group broadcast, conflict-free ((65n+s)%32 = (n+s)%32).
__global__ __launch_bounds__(64) void rescore_kernel(const float* __restrict__ x,
                                                     const float* __restrict__ sqf,
                                                     const unsigned* __restrict__ candk,
                                                     int* __restrict__ idx_out,
                                                     int* __restrict__ Bdeg){
  #pragma clang fp contract(off)
  __shared__ unsigned Mk[8][65];
  __shared__ int   sel[8][8];
  __shared__ float dex[8][8];
  int t = threadIdx.x;
  int n = t >> 3, c = t & 7;
  int g = blockIdx.x * 8 + n;

  unsigned kr[8];
  {
    const uint4* kp = (const uint4*)(candk + (size_t)g*64 + c*8);
    uint4 k0 = kp[0], k1 = kp[1];
    kr[0]=k0.x; kr[1]=k0.y; kr[2]=k0.z; kr[3]=k0.w;
    kr[4]=k1.x; kr[5]=k1.y; kr[6]=k1.z; kr[7]=k1.w;
  }
  #pragma unroll
  for (int q = 0; q < 8; ++q)
    if ((kr[q] & 16383u) == (unsigned)g) kr[q] = KEYMAX;   // drop self
  #pragma unroll
  for (int q = 0; q < 8; ++q) Mk[n][c*8+q] = kr[q];
  __syncthreads();

  int rank[8];
  #pragma unroll
  for (int q = 0; q < 8; ++q) rank[q] = 0;
  for (int s = 0; s < 64; ++s){
    unsigned ks = Mk[n][s];
    #pragma unroll
    for (int q = 0; q < 8; ++q) rank[q] += (ks < kr[q]) ? 1 : 0;
  }
  #pragma unroll
  for (int q = 0; q < 8; ++q)
    if (rank[q] < NRS) sel[n][rank[q]] = (int)(kr[q] & 16383u);
  __syncthreads();

  {
    int j = sel[n][c];
    const float4* xi = (const float4*)(x + (size_t)g * HID);
    const float4* xj = (const float4*)(x + (size_t)j * HID);
    float acc = 0.f;
    for (int k4 = 0; k4 < HID/4; ++k4){
      float4 a = xi[k4];
      float4 b = xj[k4];
      acc = fmaf(a.x, b.x, acc);
      acc = fmaf(a.y, b.y, acc);
      acc = fmaf(a.z, b.z, acc);
      acc = fmaf(a.w, b.w, acc);
    }
    float t1   = sqf[g] + sqf[j];
    float twod = 2.0f * acc;
    dex[n][c] = t1 - twod;
  }
  __syncthreads();

  if (c == 0){
    unsigned taken = 0;
    #pragma unroll
    for (int k = 0; k < 4; ++k){
      float bdv = FLTMAX; int bj = 0x7fffffff, bs = -1;
      for (int s = 0; s < NRS; ++s){
        if (taken & (1u << s)) continue;
        float d = dex[n][s]; int j = sel[n][s];
        if (d < bdv || (d == bdv && j < bj)){ bdv = d; bj = j; bs = s; }
      }
      taken |= 1u << bs;
      idx_out[g*4 + k] = bj;
      atomicAdd(&Bdeg[bj], 1);
    }
  }
}

// out[i][o] = sum_k A[i][k] * W[o][k]   (A: Mx256 f16, W staged f16, out f16)
__global__ __launch_bounds__(256) void gemm_xw(const _Float16* __restrict__ A,
                                               const _Float16* __restrict__ W,
                                               _Float16* __restrict__ out){
  __shared__ unsigned short Ws[64 * LDSK];
  int tid = threadIdx.x;
  int i0 = (blockIdx.x >> 2) * 64;
  int o0 = (blockIdx.x & 3)  * 64;
  int wave = tid >> 6, lane = tid & 63, quad = lane >> 4, lcol = lane & 15;
  load_tile64(Ws, (const unsigned short*)(W + (size_t)o0 * HID), tid);
  f16x8 a[8];
  const _Float16* arow = A + (size_t)(i0 + wave*16 + lcol) * HID + quad*8;
  #pragma unroll
  for (int ks = 0; ks < 8; ++ks) a[ks] = *(const f16x8*)(arow + ks*32);
  __syncthreads();
  #pragma unroll
  for (int sub = 0; sub < 4; ++sub){
    f32x4 acc = {0.f, 0.f, 0.f, 0.f};
    #pragma unroll
    for (int ks = 0; ks < 8; ++ks){
      f16x8 b = *(const f16x8*)&Ws[(sub*16 + lcol)*LDSK + quad*8 + ks*32];
      acc = __builtin_amdgcn_mfma_f32_16x16x32_f16(a[ks], b, acc, 0, 0, 0);
    }
    #pragma unroll
    for (int reg = 0; reg < 4; ++reg)
      out[(size_t)(i0 + wave*16 + quad*4 + reg)*HID + o0 + sub*16 + lcol] = (_Float16)acc[reg];
  }
}

__global__ __launch_bounds__(256) void prefix_kernel(const int* __restrict__ Bdeg,
                                                     int* __restrict__ off,
                                                     int* __restrict__ cursor){
  __shared__ int psum[256];
  __shared__ int excl[256];
  int t = threadIdx.x;
  int base = t * 64;
  int s = 0;
  for (int k = 0; k < 64; ++k) s += Bdeg[base + k];
  psum[t] = s;
  __syncthreads();
  if (t == 0){ int a = 0; for (int k = 0; k < 256; ++k){ excl[k] = a; a += psum[k]; } }
  __syncthreads();
  int a = excl[t];
  for (int k = 0; k < 64; ++k){ int dv = Bdeg[base + k]; off[base+k] = a; cursor[base+k] = a; a += dv; }
}

__global__ __launch_bounds__(256) void fill_kernel(const int* __restrict__ idx,
                                                   int* __restrict__ cursor,
                                                   int* __restrict__ rev){
  int i = blockIdx.x * 256 + threadIdx.x;
  #pragma unroll
  for (int t = 0; t < 4; ++t){
    int e = idx[i*4 + t];
    int p = atomicAdd(&cursor[e], 1);
    rev[p] = i;
  }
}

// E[e] = mean over contributing nodes of xt[node]  (gather via reverse CSR)
// R11-proven: wave-per-edge, lane owns 4 channels (f16x4), unroll-4 ILP.
__global__ __launch_bounds__(256) void efeat_kernel(const _Float16* __restrict__ xt,
                                                    const int* __restrict__ off,
                                                    const int* __restrict__ deg,
                                                    const int* __restrict__ rev,
                                                    _Float16* __restrict__ E){
  int wv   = blockIdx.x * 4 + (threadIdx.x >> 6);   // global wave id
  int lane = threadIdx.x & 63;
  for (int e = wv; e < NN; e += NWV){
    int o = off[e], d = deg[e];
    float s0 = 0.f, s1 = 0.f, s2 = 0.f, s3 = 0.f;
    #pragma unroll 4
    for (int k = 0; k < d; ++k){
      int node = rev[o + k];
      f16x4 v = *(const f16x4*)(xt + (size_t)node * HID + lane * 4);
      s0 += (float)v.x; s1 += (float)v.y; s2 += (float)v.z; s3 += (float)v.w;
    }
    f16x4 w;
    if (d > 0){
      float fd = (float)d;
      w.x = (_Float16)(s0 / fd); w.y = (_Float16)(s1 / fd);
      w.z = (_Float16)(s2 / fd); w.w = (_Float16)(s3 / fd);
    } else {
      w.x = (_Float16)0.f; w.y = (_Float16)0.f; w.z = (_Float16)0.f; w.w = (_Float16)0.f;
    }
    *(f16x4*)(E + (size_t)e * HID + lane * 4) = w;
  }
}

// R11-proven: wave-per-node, lane owns 4 channels; 4 independent E-row loads.
__global__ __launch_bounds__(256) void fin1_kernel(const _Float16* __restrict__ E,
                                                   const int* __restrict__ idx,
                                                   const float* __restrict__ b1,
                                                   const float* __restrict__ pa,
                                                   _Float16* __restrict__ h1){
  int wv   = blockIdx.x * 4 + (threadIdx.x >> 6);
  int lane = threadIdx.x & 63;
  float4 bc = ((const float4*)b1)[lane];
  float a   = pa[0];
  for (int i = wv; i < NN; i += NWV){
    const int* ip = idx + i*4;
    int e0 = ip[0], e1 = ip[1], e2 = ip[2], e3 = ip[3];
    f16x4 v0 = *(const f16x4*)(E + (size_t)e0*HID + lane*4);
    f16x4 v1 = *(const f16x4*)(E + (size_t)e1*HID + lane*4);
    f16x4 v2 = *(const f16x4*)(E + (size_t)e2*HID + lane*4);
    f16x4 v3 = *(const f16x4*)(E + (size_t)e3*HID + lane*4);
    f16x4 w;
    #pragma unroll
    for (int c = 0; c < 4; ++c){
      float s = ((float)v0[c] + (float)v1[c] + (float)v2[c] + (float)v3[c]);
      float acc = 0.25f * s + (&bc.x)[c];
      acc = (acc >= 0.f) ? acc : a * acc;
      w[c] = (_Float16)acc;
    }
    *(f16x4*)(h1 + (size_t)i*HID + lane*4) = w;
  }
}

__global__ __launch_bounds__(256) void fin2_kernel(const _Float16* __restrict__ E,
                                                   const int* __restrict__ idx,
                                                   const float* __restrict__ b2,
                                                   const float* __restrict__ x,
                                                   const float* __restrict__ pa,
                                                   float* __restrict__ out){
  int wv   = blockIdx.x * 4 + (threadIdx.x >> 6);
  int lane = threadIdx.x & 63;
  float4 bc = ((const float4*)b2)[lane];
  float a   = pa[0];
  for (int i = wv; i < NN; i += NWV){
    const int* ip = idx + i*4;
    int e0 = ip[0], e1 = ip[1], e2 = ip[2], e3 = ip[3];
    f16x4 v0 = *(const f16x4*)(E + (size_t)e0*HID + lane*4);
    f16x4 v1 = *(const f16x4*)(E + (size_t)e1*HID + lane*4);
    f16x4 v2 = *(const f16x4*)(E + (size_t)e2*HID + lane*4);
    f16x4 v3 = *(const f16x4*)(E + (size_t)e3*HID + lane*4);
    float4 xr = *(const float4*)(x + (size_t)i*HID + lane*4);
    float4 w;
    #pragma unroll
    for (int c = 0; c < 4; ++c){
      float s = ((float)v0[c] + (float)v1[c] + (float)v2[c] + (float)v3[c]);
      float acc = 0.25f * s + (&bc.x)[c] + (&xr.x)[c];
      acc = (acc >= 0.f) ? acc : a * acc;
      (&w.x)[c] = acc;
    }
    *(float4*)(out + (size_t)i*HID + lane*4) = w;
  }
}

extern "C" void kernel_launch(void* const* d_in, const int* in_sizes, int n_in,
                              void* d_out, int out_size, void* d_ws, size_t ws_size,
                              hipStream_t stream){
  (void)in_sizes; (void)n_in; (void)out_size; (void)ws_size;
  const float* x  = (const float*)d_in[0];
  // d_in[1] = edge_index (int32), unused by the math
  const float* W1 = (const float*)d_in[2];
  const float* b1 = (const float*)d_in[3];
  const float* W2 = (const float*)d_in[4];
  const float* b2 = (const float*)d_in[5];
  const float* pa = (const float*)d_in[6];
  float* out = (float*)d_out;

  char* ws = (char*)d_ws;
  float*  sqf    = (float*) (ws + 0);                        //  64 KB
  int*    idx    = (int*)   (ws + 65536);                    // 256 KB
  int*    Bdeg   = (int*)   (ws + 327680);                   //  64 KB
  int*    offE   = (int*)   (ws + 393216);                   //  64 KB
  int*    cursor = (int*)   (ws + 458752);                   //  64 KB
  int*    rev    = (int*)   (ws + 524288);                   // 256 KB
  _Float16* xh   = (_Float16*)(ws + (size_t)(5<<20));        //   8 MB
  _Float16* W1h  = (_Float16*)(ws + (size_t)(13<<20));       // 128 KB
  _Float16* W2h  = (_Float16*)(ws + (size_t)(13<<20) + 131072);
  _Float16* xt   = (_Float16*)(ws + (size_t)(13<<20) + 262144);            // 8 MB
  _Float16* E    = (_Float16*)(ws + (size_t)(21<<20) + 262144);            // 8 MB
  _Float16* h1   = (_Float16*)(ws + (size_t)(29<<20) + 262144);            // 8 MB
  // candk (NN*64*4B = 4 MB) aliases the xt region: dead until the first
  // gemm_xw (which runs after rescore consumed it) -> no ws growth.
  unsigned* candk = (unsigned*)xt;                           // 4 MB

  prep_kernel   <<<CVTB + NN/16, 256, 0, stream>>>(x, W1, W2, xh, W1h, W2h, sqf, Bdeg);
  knn_kernel    <<<(NN/ITILE)*NSLICE, 256, 0, stream>>>(xh, sqf, candk);
  rescore_kernel<<<NN/8, 64, 0, stream>>>(x, sqf, candk, idx, Bdeg);
  prefix_kernel <<<1, 256, 0, stream>>>(Bdeg, offE, cursor);
  fill_kernel   <<<NN/256, 256, 0, stream>>>(idx, cursor, rev);

  gemm_xw       <<<(NN/64)*4, 256, 0, stream>>>(xh, W1h, xt);
  efeat_kernel  <<<GSB, 256, 0, stream>>>(xt, offE, Bdeg, rev, E);
  fin1_kernel   <<<GSB, 256, 0, stream>>>(E, idx, b1, pa, h1);

  gemm_xw       <<<(NN/64)*4, 256, 0, stream>>>(h1, W2h, xt);
  efeat_kernel  <<<GSB, 256, 0, stream>>>(xt, offE, Bdeg, rev, E);
  fin2_kernel   <<<GSB, 256, 0, stream>>>(E, idx, b2, x, pa, out);
}

// Round 14
// 407.786 us; speedup vs baseline: 2.2030x; 1.0346x over previous
//
#include <hip/hip_runtime.h>
#include <stdint.h>

#define NN   16384
#define HID  256
#define LDSK 264            // padded LDS row stride in f16 elems (gemm body)
#define NSLICE 16           // j sliced 16-way
#define JSL  (NN/NSLICE)    // 1024 j's per slice
#define JT   32             // j-tile rows, 16KB tiles, double-buffered (R5-proven)
#define NIT  (JSL/JT)       // 32 iterations per block
#define NSETS 4             // R6-proven: LDS bytes/eval halved, no spill at (256,2)
#define ITILE (NSETS*64)    // 256 i's per block
#define NRS  8              // exact-rescore chains (top-8 of 64 by scan key)
#define GSB  2048           // grid-stride block count for efeat/fin
#define NWV  (GSB*4)        // 8192 concurrent waves for wave-per-item kernels
#define KNNB ((NN/ITILE)*NSLICE)   // 1024 knn blocks
#define GEMB ((NN/64)*4)           // 1024 gemm blocks
#define FLTMAX 3.402823466e38f
#define KEYMAX 0xFFFFFFFFu
#define VBIAS 131072.0f     // folded into sqj64; keeps v64+B > 0 for ALL pairs incl. self
#define MSTRIDE 17          // padded merge stride (u32): tid*17 reads are conflict-free

typedef __attribute__((ext_vector_type(8))) _Float16 f16x8;
typedef __attribute__((ext_vector_type(4))) _Float16 f16x4;
typedef __attribute__((ext_vector_type(4))) float f32x4;

typedef const __attribute__((address_space(1))) unsigned int* gAS1;
typedef __attribute__((address_space(3))) unsigned int* lAS3;

// ---- fused fp32->fp16 convert (x, W1, W2) + np-replicating row sum-of-squares
// ---- + Bdeg zeroing (replaces hipMemsetAsync) ----
// R8 lesson (journal): device-scope __threadfence in a 16k-block kernel costs
// ~240us on gfx950 — NO fence-based fusion; kernel boundaries are the cheap
// cross-block ordering primitive here.
// R14: gemm1 fused into the knn DISPATCH (independent-work backfill): gemm1
// depends only on prep, so its 1024 blocks ride in knn's 148us shadow instead
// of paying their own boundary. candk alias moved xt-region -> E-region
// (gemm1 now writes xt concurrently with knn writing candk).
#define NXG (NN*HID/4)
#define NWG (HID*HID/4)
#define CVTB ((NXG + 2*NWG)/256)     // 4224 cvt blocks
__global__ __launch_bounds__(256) void prep_kernel(const float* __restrict__ x,
                                                   const float* __restrict__ W1,
                                                   const float* __restrict__ W2,
                                                   _Float16* __restrict__ xh,
                                                   _Float16* __restrict__ W1h,
                                                   _Float16* __restrict__ W2h,
                                                   float* __restrict__ sqf,
                                                   int* __restrict__ Bdeg){
  #pragma clang fp contract(off)
  int b = blockIdx.x;
  int g0 = b * 256 + threadIdx.x;
  if (g0 < NN) Bdeg[g0] = 0;
  if (b < CVTB){
    int g = g0;
    const float* src; _Float16* dst; int o;
    if (g < NXG)            { src = x;  dst = xh;  o = g; }
    else if (g < NXG + NWG) { src = W1; dst = W1h; o = g - NXG; }
    else                    { src = W2; dst = W2h; o = g - NXG - NWG; }
    float4 v = ((const float4*)src)[o];
    f16x4 h; h.x = (_Float16)v.x; h.y = (_Float16)v.y; h.z = (_Float16)v.z; h.w = (_Float16)v.w;
    ((f16x4*)dst)[o] = h;
  } else {
    int bb = b - CVTB;
    int lane = threadIdx.x & 63;
    int rw   = lane >> 4;
    int h    = (lane >> 3) & 1;
    int j    = lane & 7;
    int row  = (bb * 4 + (threadIdx.x >> 6)) * 4 + rw;
    const float* p = x + (size_t)row * HID + h*128 + j;
    float v0 = p[0];
    float r  = v0 * v0;
    #pragma unroll
    for (int i = 1; i < 16; ++i){ float v = p[i*8]; float m = v * v; r = r + m; }
    float t1 = r  + __shfl_xor(r,  1);
    float t2 = t1 + __shfl_xor(t1, 2);
    float t3 = t2 + __shfl_xor(t2, 4);
    float tot = t3 + __shfl_xor(t3, 8);
    if (h == 0 && j == 0) sqf[row] = tot;
  }
}

// stage 64x256 f16 tile into LDS with padded stride (256 threads) — gemm body
__device__ __forceinline__ void load_tile64(unsigned short* dst, const unsigned short* src, int tid){
  const uint4* s = (const uint4*)src;
  #pragma unroll
  for (int r = 0; r < 8; ++r){
    int fl  = tid + (r << 8);
    int row = fl >> 5;
    int c   = fl & 31;
    *(uint4*)&dst[row*LDSK + (c << 3)] = s[fl];
  }
}

// 4-op sorted-ascending top-4 insert (R6-proven):
// b0'=min(k,b0); bN'=med3(k,b(N-1),bN)
__device__ __forceinline__ unsigned umed3(unsigned a, unsigned b, unsigned c){
  unsigned d;
  asm("v_med3_u32 %0, %1, %2, %3" : "=v"(d) : "v"(a), "v"(b), "v"(c));
  return d;
}
__device__ __forceinline__ void ins4(unsigned (&b)[4], unsigned k){
  unsigned b0 = b[0], b1 = b[1], b2 = b[2];
  b[0] = k < b0 ? k : b0;          // v_min_u32
  b[1] = umed3(k, b0, b1);
  b[2] = umed3(k, b1, b2);
  b[3] = umed3(k, b2, b[3]);
}

// out[i][o] = sum_k A[i][k] * W[o][k]   (A: Mx256 f16, W staged f16, out f16)
__device__ __forceinline__ void gemm_body(const _Float16* __restrict__ A,
                                          const _Float16* __restrict__ W,
                                          _Float16* __restrict__ out,
                                          unsigned short* Ws, int blk, int tid){
  int i0 = (blk >> 2) * 64;
  int o0 = (blk & 3)  * 64;
  int wave = tid >> 6, lane = tid & 63, quad = lane >> 4, lcol = lane & 15;
  load_tile64(Ws, (const unsigned short*)(W + (size_t)o0 * HID), tid);
  f16x8 a[8];
  const _Float16* arow = A + (size_t)(i0 + wave*16 + lcol) * HID + quad*8;
  #pragma unroll
  for (int ks = 0; ks < 8; ++ks) a[ks] = *(const f16x8*)(arow + ks*32);
  __syncthreads();
  #pragma unroll
  for (int sub = 0; sub < 4; ++sub){
    f32x4 acc = {0.f, 0.f, 0.f, 0.f};
    #pragma unroll
    for (int ks = 0; ks < 8; ++ks){
      f16x8 b = *(const f16x8*)&Ws[(sub*16 + lcol)*LDSK + quad*8 + ks*32];
      acc = __builtin_amdgcn_mfma_f32_16x16x32_f16(a[ks], b, acc, 0, 0, 0);
    }
    #pragma unroll
    for (int reg = 0; reg < 4; ++reg)
      out[(size_t)(i0 + wave*16 + quad*4 + reg)*HID + o0 + sub*16 + lcol] = (_Float16)acc[reg];
  }
}

// fp16 MFMA Gram, swapped operands, FOUR stationary i-sets/wave (R6-proven).
// XOR-swizzled row-major LDS (R5-proven). R12-proven COUNTED-VMCNT PIPELINE:
//   issue prefetch(it+1) -> s_waitcnt vmcnt(4) -> raw s_barrier (A) ->
//   compute -> lgkmcnt(0) -> raw s_barrier (B). sqj for the whole slice
//   pre-staged in the prologue. R14: blocks >= KNNB run gemm1 instead
//   (independent-work backfill; both paths only read prep outputs).
__global__ __launch_bounds__(256, 2) void knng_kernel(const _Float16* __restrict__ xh,
                                                      const float* __restrict__ sqf,
                                                      unsigned* __restrict__ candk,
                                                      const _Float16* __restrict__ W1h,
                                                      _Float16* __restrict__ xt){
  __shared__ __align__(16) unsigned char smem[36864];   // knn: 2x16KB tiles + 4KB sqjA; gemm: 33792B Ws

  int tid = threadIdx.x;
  if (blockIdx.x >= KNNB){
    gemm_body(xh, W1h, xt, (unsigned short*)smem, blockIdx.x - KNNB, tid);
    return;
  }

  unsigned short* XjB = (unsigned short*)smem;          // [2][JT*256]
  float* sqjA = (float*)(smem + 32768);                 // [JSL]

  int sl   = blockIdx.x & (NSLICE-1);
  int i0   = (blockIdx.x / NSLICE) * ITILE;
  int jb0  = sl * JSL;
  int wave = tid >> 6, lane = tid & 63, quad = lane >> 4, lcol = lane & 15;

  f16x8 bfr[NSETS][8];
  #pragma unroll
  for (int s = 0; s < NSETS; ++s){
    const _Float16* br = xh + (size_t)(i0 + s*64 + wave*16 + lcol) * HID + quad*8;
    #pragma unroll
    for (int ks = 0; ks < 8; ++ks) bfr[s][ks] = *(const f16x8*)(br + ks*32);
  }

  const _Float16* gsrc[4];
  #pragma unroll
  for (int r = 0; r < 4; ++r){
    int m   = r*256 + tid;
    int row = m >> 5;
    int ch  = m & 31;
    gsrc[r] = xh + (size_t)row * HID + ((ch ^ (row & 7)) << 3);
  }

  int b0 = lcol*512 + ((quad ^ (lcol & 3)) << 4) + (((lcol >> 2) & 1) << 6);
  int b1 = b0 ^ 64;

  unsigned bk[NSETS][4];
  #pragma unroll
  for (int s = 0; s < NSETS; ++s)
    #pragma unroll
    for (int e = 0; e < 4; ++e) bk[s][e] = KEYMAX;

  // prologue: whole-slice sqj (4 floats/thread) + tile 0; one-time full drain
  {
    float4 sv = ((const float4*)(sqf + jb0))[tid];
    float4 sw;
    sw.x = fmaf(sv.x, 64.f, VBIAS); sw.y = fmaf(sv.y, 64.f, VBIAS);
    sw.z = fmaf(sv.z, 64.f, VBIAS); sw.w = fmaf(sv.w, 64.f, VBIAS);
    ((float4*)sqjA)[tid] = sw;
    size_t joff = (size_t)jb0 * HID;
    #pragma unroll
    for (int r = 0; r < 4; ++r)
      __builtin_amdgcn_global_load_lds((gAS1)(const void*)(gsrc[r] + joff),
                                       (lAS3)(void*)&XjB[(r*256 + tid) * 8],
                                       16, 0, 0);
    asm volatile("s_waitcnt vmcnt(0) lgkmcnt(0)" ::: "memory");
  }
  __builtin_amdgcn_s_barrier();
  __builtin_amdgcn_sched_barrier(0);

  for (int it = 0; it < NIT; ++it){
    int cur = it & 1;
    if (it + 1 < NIT){
      int nb = cur ^ 1;
      int jn = jb0 + (it + 1) * JT;
      size_t joff = (size_t)jn * HID;
      #pragma unroll
      for (int r = 0; r < 4; ++r)
        __builtin_amdgcn_global_load_lds((gAS1)(const void*)(gsrc[r] + joff),
                                         (lAS3)(void*)&XjB[(size_t)nb*JT*256 + (r*256 + tid) * 8],
                                         16, 0, 0);
      asm volatile("s_waitcnt vmcnt(4)" ::: "memory");   // tile it landed; tile it+1 in flight
    } else {
      asm volatile("s_waitcnt vmcnt(0)" ::: "memory");   // final tile: nothing younger
    }
    __builtin_amdgcn_s_barrier();                        // barrier-A
    __builtin_amdgcn_sched_barrier(0);

    const char*  tb  = (const char*)&XjB[(size_t)cur*JT*256];
    const float* sjb = &sqjA[it * JT];
    int jb = jb0 + it * JT;

    #pragma unroll
    for (int sub = 0; sub < 2; ++sub){
      f32x4 acc[NSETS];
      #pragma unroll
      for (int s = 0; s < NSETS; ++s) acc[s] = (f32x4){0.f,0.f,0.f,0.f};
      #pragma unroll
      for (int ks = 0; ks < 8; ++ks){
        f16x8 a = *(const f16x8*)(tb + sub*8192 + ((ks >> 1) << 7) + ((ks & 1) ? b1 : b0));
        #pragma unroll
        for (int s = 0; s < NSETS; ++s)
          acc[s] = __builtin_amdgcn_mfma_f32_16x16x32_f16(a, bfr[s][ks], acc[s], 0, 0, 0);
      }
      float4 sj4 = *(const float4*)&sjb[sub*16 + quad*4];
      int jbase = jb + sub*16 + quad*4;
      #pragma unroll
      for (int reg = 0; reg < 4; ++reg){
        int gj = jbase + reg;
        float sj = (&sj4.x)[reg];
        #pragma unroll
        for (int s = 0; s < NSETS; ++s){
          float v64 = fmaf(-128.f, acc[s][reg], sj);   // (sj - 2*dot)*64 + VBIAS > 0 always
          unsigned kv = (unsigned)v64;                 // v_cvt_u32_f32
          unsigned key = (kv << 14) + (unsigned)gj;    // v_lshl_add_u32
          ins4(bk[s], key);
        }
      }
    }
    asm volatile("s_waitcnt lgkmcnt(0)" ::: "memory");
    __builtin_amdgcn_s_barrier();                        // barrier-B: buf[cur] reads done
    __builtin_amdgcn_sched_barrier(0);
  }

  // merge across the 4 quads per i: 16 keys -> top-4 (LDS aliased, stride 17)
  unsigned* Mk = (unsigned*)smem;          // ITILE x 17 u32 = 17408 B (<= 32768)
  #pragma unroll
  for (int s = 0; s < NSETS; ++s){
    int base = (s*64 + wave*16 + lcol)*MSTRIDE + quad*4;
    #pragma unroll
    for (int e = 0; e < 4; ++e) Mk[base+e] = bk[s][e];
  }
  __syncthreads();
  if (tid < ITILE){
    unsigned fk[4];
    #pragma unroll
    for (int e = 0; e < 4; ++e) fk[e] = KEYMAX;
    #pragma unroll
    for (int s = 0; s < 16; ++s) ins4(fk, Mk[tid*MSTRIDE + s]);
    int g = i0 + tid;
    #pragma unroll
    for (int e = 0; e < 4; ++e)
      candk[(size_t)g*(NSLICE*4) + sl*4 + e] = fk[e];
  }
}

// Rescore (R13-proven): 8 nodes per 64-thread block, ONE (node,candidate)
// chain per lane. Chain math byte-identical: ascending-k fmaf chain on fp32
// rows from global, d2 = fl32(fl32(sq_i+sq_j) - 2*acc), top-4 by (d2,index)
// lex, contract(off). Rank: keys distinct, self->KEYMAX, rank = #{smaller}.
__global__ __launch_bounds__(64) void rescore_kernel(const float* __restrict__ x,
                                                     const float* __restrict__ sqf,
                                                     const unsigned* __restrict__ candk,
                                                     int* __restrict__ idx_out,
                                                     int* __restrict__ Bdeg){
  #pragma clang fp contract(off)
  __shared__ unsigned Mk[8][65];
  __shared__ int   sel[8][8];
  __shared__ float dex[8][8];
  int t = threadIdx.x;
  int n = t >> 3, c = t & 7;
  int g = blockIdx.x * 8 + n;

  unsigned kr[8];
  {
    const uint4* kp = (const uint4*)(candk + (size_t)g*64 + c*8);
    uint4 k0 = kp[0], k1 = kp[1];
    kr[0]=k0.x; kr[1]=k0.y; kr[2]=k0.z; kr[3]=k0.w;
    kr[4]=k1.x; kr[5]=k1.y; kr[6]=k1.z; kr[7]=k1.w;
  }
  #pragma unroll
  for (int q = 0; q < 8; ++q)
    if ((kr[q] & 16383u) == (unsigned)g) kr[q] = KEYMAX;   // drop self
  #pragma unroll
  for (int q = 0; q < 8; ++q) Mk[n][c*8+q] = kr[q];
  __syncthreads();

  int rank[8];
  #pragma unroll
  for (int q = 0; q < 8; ++q) rank[q] = 0;
  for (int s = 0; s < 64; ++s){
    unsigned ks = Mk[n][s];
    #pragma unroll
    for (int q = 0; q < 8; ++q) rank[q] += (ks < kr[q]) ? 1 : 0;
  }
  #pragma unroll
  for (int q = 0; q < 8; ++q)
    if (rank[q] < NRS) sel[n][rank[q]] = (int)(kr[q] & 16383u);
  __syncthreads();

  {
    int j = sel[n][c];
    const float4* xi = (const float4*)(x + (size_t)g * HID);
    const float4* xj = (const float4*)(x + (size_t)j * HID);
    float acc = 0.f;
    for (int k4 = 0; k4 < HID/4; ++k4){
      float4 a = xi[k4];
      float4 b = xj[k4];
      acc = fmaf(a.x, b.x, acc);
      acc = fmaf(a.y, b.y, acc);
      acc = fmaf(a.z, b.z, acc);
      acc = fmaf(a.w, b.w, acc);
    }
    float t1   = sqf[g] + sqf[j];
    float twod = 2.0f * acc;
    dex[n][c] = t1 - twod;
  }
  __syncthreads();

  if (c == 0){
    unsigned taken = 0;
    #pragma unroll
    for (int k = 0; k < 4; ++k){
      float bdv = FLTMAX; int bj = 0x7fffffff, bs = -1;
      for (int s = 0; s < NRS; ++s){
        if (taken & (1u << s)) continue;
        float d = dex[n][s]; int j = sel[n][s];
        if (d < bdv || (d == bdv && j < bj)){ bdv = d; bj = j; bs = s; }
      }
      taken |= 1u << bs;
      idx_out[g*4 + k] = bj;
      atomicAdd(&Bdeg[bj], 1);
    }
  }
}

// out[i][o] = sum_k A[i][k] * W[o][k]   (A: Mx256 f16, W staged f16, out f16)
__global__ __launch_bounds__(256) void gemm_xw(const _Float16* __restrict__ A,
                                               const _Float16* __restrict__ W,
                                               _Float16* __restrict__ out){
  __shared__ unsigned short Ws[64 * LDSK];
  gemm_body(A, W, out, Ws, blockIdx.x, threadIdx.x);
}

__global__ __launch_bounds__(256) void prefix_kernel(const int* __restrict__ Bdeg,
                                                     int* __restrict__ off,
                                                     int* __restrict__ cursor){
  __shared__ int psum[256];
  __shared__ int excl[256];
  int t = threadIdx.x;
  int base = t * 64;
  int s = 0;
  for (int k = 0; k < 64; ++k) s += Bdeg[base + k];
  psum[t] = s;
  __syncthreads();
  if (t == 0){ int a = 0; for (int k = 0; k < 256; ++k){ excl[k] = a; a += psum[k]; } }
  __syncthreads();
  int a = excl[t];
  for (int k = 0; k < 64; ++k){ int dv = Bdeg[base + k]; off[base+k] = a; cursor[base+k] = a; a += dv; }
}

__global__ __launch_bounds__(256) void fill_kernel(const int* __restrict__ idx,
                                                   int* __restrict__ cursor,
                                                   int* __restrict__ rev){
  int i = blockIdx.x * 256 + threadIdx.x;
  #pragma unroll
  for (int t = 0; t < 4; ++t){
    int e = idx[i*4 + t];
    int p = atomicAdd(&cursor[e], 1);
    rev[p] = i;
  }
}

// E[e] = mean over contributing nodes of xt[node]  (gather via reverse CSR)
// R11-proven: wave-per-edge, lane owns 4 channels (f16x4), unroll-4 ILP.
__global__ __launch_bounds__(256) void efeat_kernel(const _Float16* __restrict__ xt,
                                                    const int* __restrict__ off,
                                                    const int* __restrict__ deg,
                                                    const int* __restrict__ rev,
                                                    _Float16* __restrict__ E){
  int wv   = blockIdx.x * 4 + (threadIdx.x >> 6);   // global wave id
  int lane = threadIdx.x & 63;
  for (int e = wv; e < NN; e += NWV){
    int o = off[e], d = deg[e];
    float s0 = 0.f, s1 = 0.f, s2 = 0.f, s3 = 0.f;
    #pragma unroll 4
    for (int k = 0; k < d; ++k){
      int node = rev[o + k];
      f16x4 v = *(const f16x4*)(xt + (size_t)node * HID + lane * 4);
      s0 += (float)v.x; s1 += (float)v.y; s2 += (float)v.z; s3 += (float)v.w;
    }
    f16x4 w;
    if (d > 0){
      float fd = (float)d;
      w.x = (_Float16)(s0 / fd); w.y = (_Float16)(s1 / fd);
      w.z = (_Float16)(s2 / fd); w.w = (_Float16)(s3 / fd);
    } else {
      w.x = (_Float16)0.f; w.y = (_Float16)0.f; w.z = (_Float16)0.f; w.w = (_Float16)0.f;
    }
    *(f16x4*)(E + (size_t)e * HID + lane * 4) = w;
  }
}

// R11-proven: wave-per-node, lane owns 4 channels; 4 independent E-row loads.
__global__ __launch_bounds__(256) void fin1_kernel(const _Float16* __restrict__ E,
                                                   const int* __restrict__ idx,
                                                   const float* __restrict__ b1,
                                                   const float* __restrict__ pa,
                                                   _Float16* __restrict__ h1){
  int wv   = blockIdx.x * 4 + (threadIdx.x >> 6);
  int lane = threadIdx.x & 63;
  float4 bc = ((const float4*)b1)[lane];
  float a   = pa[0];
  for (int i = wv; i < NN; i += NWV){
    const int* ip = idx + i*4;
    int e0 = ip[0], e1 = ip[1], e2 = ip[2], e3 = ip[3];
    f16x4 v0 = *(const f16x4*)(E + (size_t)e0*HID + lane*4);
    f16x4 v1 = *(const f16x4*)(E + (size_t)e1*HID + lane*4);
    f16x4 v2 = *(const f16x4*)(E + (size_t)e2*HID + lane*4);
    f16x4 v3 = *(const f16x4*)(E + (size_t)e3*HID + lane*4);
    f16x4 w;
    #pragma unroll
    for (int c = 0; c < 4; ++c){
      float s = ((float)v0[c] + (float)v1[c] + (float)v2[c] + (float)v3[c]);
      float acc = 0.25f * s + (&bc.x)[c];
      acc = (acc >= 0.f) ? acc : a * acc;
      w[c] = (_Float16)acc;
    }
    *(f16x4*)(h1 + (size_t)i*HID + lane*4) = w;
  }
}

__global__ __launch_bounds__(256) void fin2_kernel(const _Float16* __restrict__ E,
                                                   const int* __restrict__ idx,
                                                   const float* __restrict__ b2,
                                                   const float* __restrict__ x,
                                                   const float* __restrict__ pa,
                                                   float* __restrict__ out){
  int wv   = blockIdx.x * 4 + (threadIdx.x >> 6);
  int lane = threadIdx.x & 63;
  float4 bc = ((const float4*)b2)[lane];
  float a   = pa[0];
  for (int i = wv; i < NN; i += NWV){
    const int* ip = idx + i*4;
    int e0 = ip[0], e1 = ip[1], e2 = ip[2], e3 = ip[3];
    f16x4 v0 = *(const f16x4*)(E + (size_t)e0*HID + lane*4);
    f16x4 v1 = *(const f16x4*)(E + (size_t)e1*HID + lane*4);
    f16x4 v2 = *(const f16x4*)(E + (size_t)e2*HID + lane*4);
    f16x4 v3 = *(const f16x4*)(E + (size_t)e3*HID + lane*4);
    float4 xr = *(const float4*)(x + (size_t)i*HID + lane*4);
    float4 w;
    #pragma unroll
    for (int c = 0; c < 4; ++c){
      float s = ((float)v0[c] + (float)v1[c] + (float)v2[c] + (float)v3[c]);
      float acc = 0.25f * s + (&bc.x)[c] + (&xr.x)[c];
      acc = (acc >= 0.f) ? acc : a * acc;
      (&w.x)[c] = acc;
    }
    *(float4*)(out + (size_t)i*HID + lane*4) = w;
  }
}

extern "C" void kernel_launch(void* const* d_in, const int* in_sizes, int n_in,
                              void* d_out, int out_size, void* d_ws, size_t ws_size,
                              hipStream_t stream){
  (void)in_sizes; (void)n_in; (void)out_size; (void)ws_size;
  const float* x  = (const float*)d_in[0];
  // d_in[1] = edge_index (int32), unused by the math
  const float* W1 = (const float*)d_in[2];
  const float* b1 = (const float*)d_in[3];
  const float* W2 = (const float*)d_in[4];
  const float* b2 = (const float*)d_in[5];
  const float* pa = (const float*)d_in[6];
  float* out = (float*)d_out;

  char* ws = (char*)d_ws;
  float*  sqf    = (float*) (ws + 0);                        //  64 KB
  int*    idx    = (int*)   (ws + 65536);                    // 256 KB
  int*    Bdeg   = (int*)   (ws + 327680);                   //  64 KB
  int*    offE   = (int*)   (ws + 393216);                   //  64 KB
  int*    cursor = (int*)   (ws + 458752);                   //  64 KB
  int*    rev    = (int*)   (ws + 524288);                   // 256 KB
  _Float16* xh   = (_Float16*)(ws + (size_t)(5<<20));        //   8 MB
  _Float16* W1h  = (_Float16*)(ws + (size_t)(13<<20));       // 128 KB
  _Float16* W2h  = (_Float16*)(ws + (size_t)(13<<20) + 131072);
  _Float16* xt   = (_Float16*)(ws + (size_t)(13<<20) + 262144);            // 8 MB
  _Float16* E    = (_Float16*)(ws + (size_t)(21<<20) + 262144);            // 8 MB
  _Float16* h1   = (_Float16*)(ws + (size_t)(29<<20) + 262144);            // 8 MB
  // R14: candk (4 MB) now aliases the E region (NOT xt — gemm1 writes xt
  // concurrently with knn writing candk in the fused dispatch). Timeline:
  // fused kernel writes candk(E) -> rescore reads it -> efeat1 overwrites E
  // -> fin1 reads E. No ws growth.
  unsigned* candk = (unsigned*)E;                            // 4 MB

  prep_kernel   <<<CVTB + NN/16, 256, 0, stream>>>(x, W1, W2, xh, W1h, W2h, sqf, Bdeg);
  knng_kernel   <<<KNNB + GEMB, 256, 0, stream>>>(xh, sqf, candk, W1h, xt);
  rescore_kernel<<<NN/8, 64, 0, stream>>>(x, sqf, candk, idx, Bdeg);
  prefix_kernel <<<1, 256, 0, stream>>>(Bdeg, offE, cursor);
  fill_kernel   <<<NN/256, 256, 0, stream>>>(idx, cursor, rev);

  efeat_kernel  <<<GSB, 256, 0, stream>>>(xt, offE, Bdeg, rev, E);
  fin1_kernel   <<<GSB, 256, 0, stream>>>(E, idx, b1, pa, h1);

  gemm_xw       <<<(NN/64)*4, 256, 0, stream>>>(h1, W2h, xt);
  efeat_kernel  <<<GSB, 256, 0, stream>>>(xt, offE, Bdeg, rev, E);
  fin2_kernel   <<<GSB, 256, 0, stream>>>(E, idx, b2, x, pa, out);
}